// Round 4
// baseline (2569.438 us; speedup 1.0000x reference)
//
#include <hip/hip_runtime.h>
#include <hip/hip_bf16.h>

// Problem constants (from reference)
#define NN   50000
#define EE   1600000
#define INC  128
#define HH   64
#define OUTC 40
#define ALPHA 0.8f
#define LN_EPS 1e-5f
#define NB_SCAN 196   // ceil(NN/256)

// ---------------------------------------------------------------------------
// DPP wave64 sum -> total broadcast via readlane(63). VALU pipe only.
// ---------------------------------------------------------------------------
template <int CTRL, int MASK>
__device__ __forceinline__ float dpp_add(float v) {
    int r = __builtin_amdgcn_update_dpp(0, __float_as_int(v), CTRL, MASK, 0xf, true);
    return v + __int_as_float(r);
}
__device__ __forceinline__ float wavesum_bcast(float v) {
    v = dpp_add<0x111, 0xf>(v);   // row_shr:1
    v = dpp_add<0x112, 0xf>(v);   // row_shr:2
    v = dpp_add<0x114, 0xf>(v);   // row_shr:4
    v = dpp_add<0x118, 0xf>(v);   // row_shr:8
    v = dpp_add<0x142, 0xa>(v);   // row_bcast:15
    v = dpp_add<0x143, 0xc>(v);   // row_bcast:31 -> lane63 = total
    return __int_as_float(__builtin_amdgcn_readlane(__float_as_int(v), 63));
}

__device__ __forceinline__ float fast_tanh(float x) {
    // tanh(x) = sign(x) * (1-e)/(1+e), e = 2^(-2*log2(e)*|x|)
    float e = __builtin_amdgcn_exp2f(-2.8853900817779268f * __builtin_fabsf(x));
    float t = (1.0f - e) * __builtin_amdgcn_rcpf(1.0f + e);
    return __builtin_copysignf(t, x);
}

// ---------------------------------------------------------------------------
// CSR build: incidence list. ei is [2,E] flat int32.
// ---------------------------------------------------------------------------
__global__ __launch_bounds__(256) void csr_count(const int* __restrict__ ei,
                                                 int* __restrict__ cnt) {
    int i = blockIdx.x * 256 + threadIdx.x;
    if (i < 2 * EE) atomicAdd(&cnt[ei[i]], 1);
}

__global__ __launch_bounds__(256) void scanA(const int* __restrict__ cnt,
                                             int* __restrict__ offs,
                                             int* __restrict__ bsum) {
    __shared__ int tmp[256];
    int i = blockIdx.x * 256 + threadIdx.x;
    int v = (i < NN) ? cnt[i] : 0;
    tmp[threadIdx.x] = v;
    __syncthreads();
    int acc = v;
    for (int d = 1; d < 256; d <<= 1) {
        int t = (threadIdx.x >= d) ? tmp[threadIdx.x - d] : 0;
        __syncthreads();
        acc += t;
        tmp[threadIdx.x] = acc;
        __syncthreads();
    }
    if (i < NN) offs[i] = acc - v;
    if (threadIdx.x == 255) bsum[blockIdx.x] = acc;
}

__global__ __launch_bounds__(256) void scanB(int* __restrict__ bsum) {
    __shared__ int tmp[256];
    int v = (threadIdx.x < NB_SCAN) ? bsum[threadIdx.x] : 0;
    tmp[threadIdx.x] = v;
    __syncthreads();
    int acc = v;
    for (int d = 1; d < 256; d <<= 1) {
        int t = (threadIdx.x >= d) ? tmp[threadIdx.x - d] : 0;
        __syncthreads();
        acc += t;
        tmp[threadIdx.x] = acc;
        __syncthreads();
    }
    if (threadIdx.x < NB_SCAN) bsum[threadIdx.x] = acc - v;
}

__global__ __launch_bounds__(256) void scanC(int* __restrict__ offs,
                                             int* __restrict__ cur,
                                             const int* __restrict__ bsum) {
    int i = blockIdx.x * 256 + threadIdx.x;
    if (i < NN) {
        int o = offs[i] + bsum[blockIdx.x];
        offs[i] = o;
        cur[i]  = o;
    }
}

__global__ __launch_bounds__(256) void csr_fill(const int* __restrict__ ei,
                                                int* __restrict__ cur,
                                                int* __restrict__ adj) {
    int i = blockIdx.x * 256 + threadIdx.x;
    if (i >= 2 * EE) return;
    int node  = ei[i];
    int role  = (i >= EE) ? 1 : 0;
    int other = role ? ei[i - EE] : ei[i + EE];   // node ids < 65536: fit 16 bits
    int p = atomicAdd(&cur[node], 1);
    adj[p] = other | (role << 31);
}

// ---------------------------------------------------------------------------
// G = W @ W^T  (64x64). One block.
// ---------------------------------------------------------------------------
__global__ __launch_bounds__(256) void make_G(const float* __restrict__ W,
                                              float* __restrict__ G) {
    __shared__ float Ws[64 * 64];
    for (int t = threadIdx.x; t < 64 * 64; t += 256) Ws[t] = W[t];
    __syncthreads();
    for (int t = threadIdx.x; t < 64 * 64; t += 256) {
        int i = t >> 6, j = t & 63;
        float acc = 0.f;
#pragma unroll 8
        for (int k = 0; k < 64; ++k) acc += Ws[i * 64 + k] * Ws[j * 64 + k];
        G[t] = acc;
    }
}

// ---------------------------------------------------------------------------
// extractor: xh = x@We^T + be ; h0 = xh@U^T + bU ; xU = h0 / nf
// ---------------------------------------------------------------------------
__global__ __launch_bounds__(256) void extractor(
        const float* __restrict__ x, const float* __restrict__ nf,
        const float* __restrict__ We, const float* __restrict__ be,
        const float* __restrict__ U,  const float* __restrict__ bU,
        float* __restrict__ xh, float* __restrict__ xU, float* __restrict__ h0) {
    __shared__ float WeT[INC * HH];
    __shared__ float UT[HH * HH];
    __shared__ float beS[HH], bUS[HH];
    __shared__ float xs[4][INC];
    __shared__ float xhs[4][HH];

    for (int t = threadIdx.x; t < INC * HH; t += 256) {
        int j = t >> 7, k = t & 127;
        WeT[k * 64 + j] = We[t];
    }
    for (int t = threadIdx.x; t < HH * HH; t += 256) {
        int j = t >> 6, k = t & 63;
        UT[k * 64 + j] = U[t];
    }
    if (threadIdx.x < 64) { beS[threadIdx.x] = be[threadIdx.x]; bUS[threadIdx.x] = bU[threadIdx.x]; }
    __syncthreads();

    int lane = threadIdx.x & 63;
    int wv   = threadIdx.x >> 6;

    for (int n0 = blockIdx.x * 4; n0 < NN; n0 += gridDim.x * 4) {
        int n = n0 + wv;
        bool valid = n < NN;
        if (valid) {
            xs[wv][lane]      = x[(size_t)n * INC + lane];
            xs[wv][lane + 64] = x[(size_t)n * INC + lane + 64];
        }
        __syncthreads();
        float acc = beS[lane];
        if (valid) {
#pragma unroll 8
            for (int k = 0; k < INC; ++k) acc += xs[wv][k] * WeT[k * 64 + lane];
            xh[n * 64 + lane] = acc;
            xhs[wv][lane] = acc;
        }
        __syncthreads();
        if (valid) {
            float acc2 = bUS[lane];
#pragma unroll 8
            for (int k = 0; k < HH; ++k) acc2 += xhs[wv][k] * UT[k * 64 + lane];
            h0[n * 64 + lane] = acc2;
            xU[n * 64 + lane] = acc2 / nf[n];
        }
        __syncthreads();
    }
}

// ---------------------------------------------------------------------------
// fused step, LDS-transpose LN batching.
// Per node (one wave, lane = channel), per 32-edge group:
//  A (lane=ch): d = tanh(hn - h[other]) -> D[j][ch] in LDS   (32x65 fp32 tile)
//  B (lane=j, both half-waves duplicate): mu[j], rsig[j] from row sums
//  C (lane=ch): T[ch] += sum_j rsig[j]*D[j][ch]; S += sum_j rsig[j]*mu[j]
// Node epilogue: av = nf*(g*(T-S) + (deg-2*ncol)*b); p = av@G; y/s/h update.
// All LDS ops single-wave (in-order per wave, no barriers). No atomics.
// ---------------------------------------------------------------------------
__global__ __launch_bounds__(256) void fused_step(
        const int* __restrict__ adj, const int* __restrict__ offs,
        const int* __restrict__ cnt,
        const float* __restrict__ hcur, float* __restrict__ hnxt,
        const float* __restrict__ nf, const float* __restrict__ gamma,
        const float* __restrict__ beta, const float* __restrict__ Gm,
        const float* __restrict__ xU,
        float* __restrict__ y, float* __restrict__ s, int last) {
    __shared__ float Gs[64 * 64];        // 16.4 KB
    __shared__ float Dl[4][32 * 65];     // 33.3 KB: per-wave 32x65 tile
    for (int t = threadIdx.x; t < 64 * 64; t += 256) Gs[t] = Gm[t];
    __syncthreads();

    int lane = threadIdx.x & 63, wv = threadIdx.x >> 6;
    float* Dw = &Dl[wv][0];
    float g = gamma[lane], b = beta[lane];
    int jrow = lane & 31;                // phase-B row (duplicated half-waves)

    int nwaves = gridDim.x * 4;
    for (int n = blockIdx.x * 4 + wv; n < NN; n += nwaves) {
        int base = offs[n], deg = cnt[n];
        float hn = hcur[n * 64 + lane];
        float T = 0.f;          // per-channel weighted sum
        float accS = 0.f;       // scalar sum rsig*mu
        int ncol = 0;

        for (int c = 0; c < deg; c += 64) {
            int rem = deg - c;
            int nv  = rem < 64 ? rem : 64;
            int ev  = 0;
            if (lane < nv) ev = adj[base + c + lane];
            ncol += __builtin_popcountll(__ballot(ev < 0));

            for (int sub = 0; sub < nv; sub += 32) {
                int nvs = nv - sub; nvs = nvs < 32 ? nvs : 32;

                // ---- phase A: gather + tanh -> LDS tile (2-deep prefetch)
                {
                    int e0 = __builtin_amdgcn_readlane(ev, sub);
                    float hoA = hcur[(e0 & 0xffff) * 64 + lane];
                    float hoB = 0.f;
                    if (nvs > 1) {
                        int e1 = __builtin_amdgcn_readlane(ev, sub + 1);
                        hoB = hcur[(e1 & 0xffff) * 64 + lane];
                    }
                    for (int j = 0; j < nvs; ++j) {
                        float hoc = hoA;
                        hoA = hoB;
                        if (j + 2 < nvs) {
                            int e2 = __builtin_amdgcn_readlane(ev, sub + j + 2);
                            hoB = hcur[(e2 & 0xffff) * 64 + lane];
                        }
                        Dw[j * 65 + lane] = fast_tanh(hn - hoc);
                    }
                }

                // ---- phase B: per-edge LN stats (lane=j, halves duplicate)
                float s1 = 0.f, s2 = 0.f;
#pragma unroll 8
                for (int ch = 0; ch < 64; ++ch) {
                    float v = Dw[jrow * 65 + ch];
                    s1 += v;
                    s2 = __builtin_fmaf(v, v, s2);
                }
                float mu  = s1 * 0.015625f;
                float var = s2 * 0.015625f - mu * mu;
                var = var > 0.f ? var : 0.f;
                float rsig = __frsqrt_rn(var + LN_EPS);

                // ---- S partial: sum_{j<nvs} rsig[j]*mu[j]
                float pm = (lane < nvs) ? mu * rsig : 0.f;
                accS += wavesum_bcast(pm);

                // ---- phase C: T[ch] += sum_j rsig[j]*D[j][ch]
                int rsi = __float_as_int(rsig);
#pragma unroll 4
                for (int jj = 0; jj < nvs; ++jj) {
                    float rs = __int_as_float(__builtin_amdgcn_readlane(rsi, jj));
                    T = __builtin_fmaf(Dw[jj * 65 + lane], rs, T);
                }
            }
        }

        float nfn = nf[n];
        float av  = nfn * (g * (T - accS) + (float)(deg - 2 * ncol) * b);

        // p[lane] = sum_k av(lane k) * G[k][lane] via readlane broadcast
        float p = 0.f;
        int avi = __float_as_int(av);
#pragma unroll
        for (int k = 0; k < 64; ++k) {
            float ak = __int_as_float(__builtin_amdgcn_readlane(avi, k));
            p = __builtin_fmaf(ak, Gs[k * 64 + lane], p);
        }

        float yv = -ALPHA * p + (1.0f - ALPHA) * y[n * 64 + lane];
        y[n * 64 + lane] = yv;
        s[n * 64 + lane] = (1.0f - ALPHA) * s[n * 64 + lane] + av;
        if (!last) hnxt[n * 64 + lane] = nfn * (yv + xU[n * 64 + lane]);
    }
}

// ---------------------------------------------------------------------------
// final: z = -alpha*(s@W) ; zf = nf*z + xh ; out = zf@Wlast^T + blast
// ---------------------------------------------------------------------------
__global__ __launch_bounds__(256) void final_out(
        const float* __restrict__ s, const float* __restrict__ xh,
        const float* __restrict__ nf, const float* __restrict__ W,
        const float* __restrict__ Wlast, const float* __restrict__ blast,
        float* __restrict__ out) {
    __shared__ float Ws[64 * 64];
    __shared__ float WlT[64 * OUTC];
    __shared__ float blS[OUTC];
    __shared__ float ss[4][64];
    __shared__ float zfs[4][64];
    for (int t = threadIdx.x; t < 64 * 64; t += 256) Ws[t] = W[t];
    for (int t = threadIdx.x; t < OUTC * 64; t += 256) {
        int o = t >> 6, j = t & 63;
        WlT[j * OUTC + o] = Wlast[t];
    }
    if (threadIdx.x < OUTC) blS[threadIdx.x] = blast[threadIdx.x];
    __syncthreads();
    int lane = threadIdx.x & 63, wv = threadIdx.x >> 6;
    for (int n0 = blockIdx.x * 4; n0 < NN; n0 += gridDim.x * 4) {
        int n = n0 + wv;
        if (n < NN) ss[wv][lane] = s[n * 64 + lane];
        __syncthreads();
        if (n < NN) {
            float z = 0.f;
#pragma unroll 8
            for (int k = 0; k < 64; ++k) z += ss[wv][k] * Ws[k * 64 + lane];
            z *= -ALPHA;
            zfs[wv][lane] = nf[n] * z + xh[n * 64 + lane];
        }
        __syncthreads();
        if (n < NN && lane < OUTC) {
            float acc = blS[lane];
#pragma unroll 8
            for (int j = 0; j < 64; ++j) acc += zfs[wv][j] * WlT[j * OUTC + lane];
            out[n * OUTC + lane] = acc;
        }
        __syncthreads();
    }
}

// ---------------------------------------------------------------------------
extern "C" void kernel_launch(void* const* d_in, const int* in_sizes, int n_in,
                              void* d_out, int out_size, void* d_ws, size_t ws_size,
                              hipStream_t stream) {
    const float* x     = (const float*)d_in[0];
    const int*   ei    = (const int*)  d_in[1];
    const float* nf    = (const float*)d_in[2];
    const float* We    = (const float*)d_in[3];
    const float* be    = (const float*)d_in[4];
    const float* W     = (const float*)d_in[5];
    const float* U     = (const float*)d_in[6];
    const float* bU    = (const float*)d_in[7];
    const float* gamma = (const float*)d_in[8];
    const float* beta  = (const float*)d_in[9];
    const float* Wlast = (const float*)d_in[10];
    const float* blast = (const float*)d_in[11];
    float* out = (float*)d_out;

    char* ws = (char*)d_ws;
    size_t off = 0;
    const size_t NH = (size_t)NN * HH * sizeof(float);
    int*   adj  = (int*)(ws + off);   off += (size_t)2 * EE * sizeof(int);
    int*   offs = (int*)(ws + off);   off += (size_t)NN * sizeof(int);
    int*   cnt  = (int*)(ws + off);   off += (size_t)NN * sizeof(int);
    int*   cur  = (int*)(ws + off);   off += (size_t)NN * sizeof(int);
    int*   bsum = (int*)(ws + off);   off += 256 * sizeof(int);
    float* xh   = (float*)(ws + off); off += NH;
    float* xU   = (float*)(ws + off); off += NH;
    float* h0   = (float*)(ws + off); off += NH;
    float* h1   = (float*)(ws + off); off += NH;
    float* y    = (float*)(ws + off); off += NH;
    float* s    = (float*)(ws + off); off += NH;
    float* G    = (float*)(ws + off); off += (size_t)HH * HH * sizeof(float);

    hipMemsetAsync(cnt, 0, (size_t)NN * sizeof(int), stream);
    hipMemsetAsync(y, 0, 2 * NH, stream);   // y and s are adjacent

    // CSR build (once per launch)
    csr_count<<<(2 * EE + 255) / 256, 256, 0, stream>>>(ei, cnt);
    scanA<<<NB_SCAN, 256, 0, stream>>>(cnt, offs, bsum);
    scanB<<<1, 256, 0, stream>>>(bsum);
    scanC<<<NB_SCAN, 256, 0, stream>>>(offs, cur, bsum);
    csr_fill<<<(2 * EE + 255) / 256, 256, 0, stream>>>(ei, cur, adj);

    make_G<<<1, 256, 0, stream>>>(W, G);
    extractor<<<512, 256, 0, stream>>>(x, nf, We, be, U, bU, xh, xU, h0);

    float* hc = h0;
    float* hn = h1;
    for (int t = 0; t < 4; ++t) {
        // 3 blocks/CU (49.7 KB LDS each) x 256 CUs = 768 resident blocks
        fused_step<<<768, 256, 0, stream>>>(adj, offs, cnt, hc, hn, nf, gamma,
                                            beta, G, xU, y, s, t == 3);
        float* tmp = hc; hc = hn; hn = tmp;
    }
    final_out<<<512, 256, 0, stream>>>(s, xh, nf, W, Wlast, blast, out);
}

// Round 5
// 2153.713 us; speedup vs baseline: 1.1930x; 1.1930x over previous
//
#include <hip/hip_runtime.h>
#include <hip/hip_bf16.h>

// Problem constants (from reference)
#define NN   50000
#define EE   1600000
#define INC  128
#define HH   64
#define OUTC 40
#define ALPHA 0.8f
#define LN_EPS 1e-5f
#define NB_SCAN 196   // ceil(NN/256)

// ---------------------------------------------------------------------------
// DPP wave64 sum, N independent chains in lock-step (guaranteed interleave).
// Result broadcast to all lanes via readlane(63).
// ---------------------------------------------------------------------------
#define DPP_STAGE(CTRL, MASK)                                                  \
    _Pragma("unroll")                                                          \
    for (int _i = 0; _i < N; ++_i) {                                           \
        int _r = __builtin_amdgcn_update_dpp(0, __float_as_int(v[_i]),         \
                                             CTRL, MASK, 0xf, true);           \
        v[_i] += __int_as_float(_r);                                           \
    }

template <int N>
__device__ __forceinline__ void wavesum_bcastN(float* v) {
    DPP_STAGE(0x111, 0xf)   // row_shr:1
    DPP_STAGE(0x112, 0xf)   // row_shr:2
    DPP_STAGE(0x114, 0xf)   // row_shr:4
    DPP_STAGE(0x118, 0xf)   // row_shr:8
    DPP_STAGE(0x142, 0xa)   // row_bcast:15
    DPP_STAGE(0x143, 0xc)   // row_bcast:31 -> lane63 = total
#pragma unroll
    for (int i = 0; i < N; ++i)
        v[i] = __int_as_float(__builtin_amdgcn_readlane(__float_as_int(v[i]), 63));
}

__device__ __forceinline__ float wavesum_bcast(float x) {
    float v[1] = {x};
    wavesum_bcastN<1>(v);
    return v[0];
}

__device__ __forceinline__ float fast_tanh(float x) {
    float e = __builtin_amdgcn_exp2f(-2.8853900817779268f * __builtin_fabsf(x));
    float t = (1.0f - e) * __builtin_amdgcn_rcpf(1.0f + e);
    return __builtin_copysignf(t, x);
}

// ---------------------------------------------------------------------------
// CSR build. ei is [2,E] flat int32. mode=1: adj stores edge_id | role<<31
// (fast path). mode=0: adj stores other-endpoint | role<<31 (fallback path).
// ---------------------------------------------------------------------------
__global__ __launch_bounds__(256) void csr_count(const int* __restrict__ ei,
                                                 int* __restrict__ cnt) {
    int i = blockIdx.x * 256 + threadIdx.x;
    if (i < 2 * EE) atomicAdd(&cnt[ei[i]], 1);
}

__global__ __launch_bounds__(256) void scanA(const int* __restrict__ cnt,
                                             int* __restrict__ offs,
                                             int* __restrict__ bsum) {
    __shared__ int tmp[256];
    int i = blockIdx.x * 256 + threadIdx.x;
    int v = (i < NN) ? cnt[i] : 0;
    tmp[threadIdx.x] = v;
    __syncthreads();
    int acc = v;
    for (int d = 1; d < 256; d <<= 1) {
        int t = (threadIdx.x >= d) ? tmp[threadIdx.x - d] : 0;
        __syncthreads();
        acc += t;
        tmp[threadIdx.x] = acc;
        __syncthreads();
    }
    if (i < NN) offs[i] = acc - v;
    if (threadIdx.x == 255) bsum[blockIdx.x] = acc;
}

__global__ __launch_bounds__(256) void scanB(int* __restrict__ bsum) {
    __shared__ int tmp[256];
    int v = (threadIdx.x < NB_SCAN) ? bsum[threadIdx.x] : 0;
    tmp[threadIdx.x] = v;
    __syncthreads();
    int acc = v;
    for (int d = 1; d < 256; d <<= 1) {
        int t = (threadIdx.x >= d) ? tmp[threadIdx.x - d] : 0;
        __syncthreads();
        acc += t;
        tmp[threadIdx.x] = acc;
        __syncthreads();
    }
    if (threadIdx.x < NB_SCAN) bsum[threadIdx.x] = acc - v;
}

__global__ __launch_bounds__(256) void scanC(int* __restrict__ offs,
                                             int* __restrict__ cur,
                                             const int* __restrict__ bsum) {
    int i = blockIdx.x * 256 + threadIdx.x;
    if (i < NN) {
        int o = offs[i] + bsum[blockIdx.x];
        offs[i] = o;
        cur[i]  = o;
    }
}

__global__ __launch_bounds__(256) void csr_fill(const int* __restrict__ ei,
                                                int* __restrict__ cur,
                                                int* __restrict__ adj,
                                                int mode) {
    int i = blockIdx.x * 256 + threadIdx.x;
    if (i >= 2 * EE) return;
    int node = ei[i];
    int role = (i >= EE) ? 1 : 0;
    int payload;
    if (mode) payload = (role ? i - EE : i);          // edge id
    else      payload = (role ? ei[i - EE] : ei[i + EE]);  // other endpoint
    int p = atomicAdd(&cur[node], 1);
    adj[p] = payload | (role << 31);
}

// ---------------------------------------------------------------------------
// G = W @ W^T  (64x64). One block.
// ---------------------------------------------------------------------------
__global__ __launch_bounds__(256) void make_G(const float* __restrict__ W,
                                              float* __restrict__ G) {
    __shared__ float Ws[64 * 64];
    for (int t = threadIdx.x; t < 64 * 64; t += 256) Ws[t] = W[t];
    __syncthreads();
    for (int t = threadIdx.x; t < 64 * 64; t += 256) {
        int i = t >> 6, j = t & 63;
        float acc = 0.f;
#pragma unroll 8
        for (int k = 0; k < 64; ++k) acc += Ws[i * 64 + k] * Ws[j * 64 + k];
        G[t] = acc;
    }
}

// ---------------------------------------------------------------------------
// extractor: xh = x@We^T + be ; h0 = xh@U^T + bU ; xU = h0 / nf
// ---------------------------------------------------------------------------
__global__ __launch_bounds__(256) void extractor(
        const float* __restrict__ x, const float* __restrict__ nf,
        const float* __restrict__ We, const float* __restrict__ be,
        const float* __restrict__ U,  const float* __restrict__ bU,
        float* __restrict__ xh, float* __restrict__ xU, float* __restrict__ h0) {
    __shared__ float WeT[INC * HH];
    __shared__ float UT[HH * HH];
    __shared__ float beS[HH], bUS[HH];
    __shared__ float xs[4][INC];
    __shared__ float xhs[4][HH];

    for (int t = threadIdx.x; t < INC * HH; t += 256) {
        int j = t >> 7, k = t & 127;
        WeT[k * 64 + j] = We[t];
    }
    for (int t = threadIdx.x; t < HH * HH; t += 256) {
        int j = t >> 6, k = t & 63;
        UT[k * 64 + j] = U[t];
    }
    if (threadIdx.x < 64) { beS[threadIdx.x] = be[threadIdx.x]; bUS[threadIdx.x] = bU[threadIdx.x]; }
    __syncthreads();

    int lane = threadIdx.x & 63;
    int wv   = threadIdx.x >> 6;

    for (int n0 = blockIdx.x * 4; n0 < NN; n0 += gridDim.x * 4) {
        int n = n0 + wv;
        bool valid = n < NN;
        if (valid) {
            xs[wv][lane]      = x[(size_t)n * INC + lane];
            xs[wv][lane + 64] = x[(size_t)n * INC + lane + 64];
        }
        __syncthreads();
        float acc = beS[lane];
        if (valid) {
#pragma unroll 8
            for (int k = 0; k < INC; ++k) acc += xs[wv][k] * WeT[k * 64 + lane];
            xh[n * 64 + lane] = acc;
            xhs[wv][lane] = acc;
        }
        __syncthreads();
        if (valid) {
            float acc2 = bUS[lane];
#pragma unroll 8
            for (int k = 0; k < HH; ++k) acc2 += xhs[wv][k] * UT[k * 64 + lane];
            h0[n * 64 + lane] = acc2;
            xU[n * 64 + lane] = acc2 / nf[n];
        }
        __syncthreads();
    }
}

// ---------------------------------------------------------------------------
// FAST PATH kernel A: one canonical message per edge.
// Wave handles 64-edge chunks; 4-edge groups, rolling 1-group prefetch,
// 8 lock-step DPP chains. m = g*(d-mu)*rsig + b stored fp16 [E,64].
// EE % 64 == 0, so all chunks are full.
// ---------------------------------------------------------------------------
__global__ __launch_bounds__(256) void edge_msg(
        const int* __restrict__ ei, const float* __restrict__ hcur,
        const float* __restrict__ gamma, const float* __restrict__ beta,
        _Float16* __restrict__ m16) {
    int lane = threadIdx.x & 63, wv = threadIdx.x >> 6;
    float g = gamma[lane], b = beta[lane];
    int wid = blockIdx.x * 4 + wv;
    int nw  = gridDim.x * 4;

    for (int e0 = wid * 64; e0 < EE; e0 += nw * 64) {
        int rv = ei[e0 + lane];
        int cv = ei[EE + e0 + lane];

        float hr[4], hc[4], hrn[4], hcn[4];
#pragma unroll
        for (int i = 0; i < 4; ++i) {
            int rr = __builtin_amdgcn_readlane(rv, i);
            int cc = __builtin_amdgcn_readlane(cv, i);
            hr[i] = hcur[rr * 64 + lane];
            hc[i] = hcur[cc * 64 + lane];
        }

        for (int j = 0; j < 64; j += 4) {
            if (j + 4 < 64) {
#pragma unroll
                for (int i = 0; i < 4; ++i) {
                    int rr = __builtin_amdgcn_readlane(rv, j + 4 + i);
                    int cc = __builtin_amdgcn_readlane(cv, j + 4 + i);
                    hrn[i] = hcur[rr * 64 + lane];
                    hcn[i] = hcur[cc * 64 + lane];
                }
            }
            float d[4], ss[8];
#pragma unroll
            for (int i = 0; i < 4; ++i) {
                d[i] = fast_tanh(hr[i] - hc[i]);
                ss[i]     = d[i];
                ss[i + 4] = d[i] * d[i];
            }
            wavesum_bcastN<8>(ss);
#pragma unroll
            for (int i = 0; i < 4; ++i) {
                float mu  = ss[i] * 0.015625f;
                float var = ss[i + 4] * 0.015625f - mu * mu;
                var = var > 0.f ? var : 0.f;
                float rsig = __frsqrt_rn(var + LN_EPS);
                float gr = g * rsig;
                float m  = __builtin_fmaf(gr, d[i],
                            __builtin_fmaf(-gr, mu, b));
                m16[(size_t)(e0 + j + i) * 64 + lane] = (_Float16)m;
            }
#pragma unroll
            for (int i = 0; i < 4; ++i) { hr[i] = hrn[i]; hc[i] = hcn[i]; }
        }
    }
}

// ---------------------------------------------------------------------------
// FAST PATH kernel B: per node, sum +/- m16 rows over incidences (sign =
// role), then epilogue: av = nf*T ; p = av@G ; y/s/h updates.
// ---------------------------------------------------------------------------
__global__ __launch_bounds__(256) void gather_update(
        const int* __restrict__ adj, const int* __restrict__ offs,
        const int* __restrict__ cnt, const _Float16* __restrict__ m16,
        const float* __restrict__ nf, const float* __restrict__ Gm,
        const float* __restrict__ xU,
        float* __restrict__ y, float* __restrict__ s,
        float* __restrict__ hnxt, int last) {
    __shared__ float Gs[64 * 64];
    for (int t = threadIdx.x; t < 64 * 64; t += 256) Gs[t] = Gm[t];
    __syncthreads();

    int lane = threadIdx.x & 63, wv = threadIdx.x >> 6;
    int nwaves = gridDim.x * 4;

    for (int n = blockIdx.x * 4 + wv; n < NN; n += nwaves) {
        int base = offs[n], deg = cnt[n];
        float T = 0.f;

        for (int c = 0; c < deg; c += 64) {
            int rem = deg - c;
            int nv  = rem < 64 ? rem : 64;
            int ev  = 0;
            if (lane < nv) ev = adj[base + c + lane];

            for (int j = 0; j < nv; j += 8) {
                int lim = nv - j; lim = lim < 8 ? lim : 8;
                float vals[8], sg[8];
#pragma unroll
                for (int i = 0; i < 8; ++i) {
                    if (i < lim) {
                        int er = __builtin_amdgcn_readlane(ev, j + i);
                        unsigned eid = (unsigned)er & 0x7fffffffu;
                        sg[i]   = (er < 0) ? -1.0f : 1.0f;
                        vals[i] = (float)m16[(size_t)eid * 64 + lane];
                    }
                }
#pragma unroll
                for (int i = 0; i < 8; ++i)
                    if (i < lim) T = __builtin_fmaf(vals[i], sg[i], T);
            }
        }

        float nfn = nf[n];
        float av  = nfn * T;

        float p = 0.f;
        int avi = __float_as_int(av);
#pragma unroll
        for (int k = 0; k < 64; ++k) {
            float ak = __int_as_float(__builtin_amdgcn_readlane(avi, k));
            p = __builtin_fmaf(ak, Gs[k * 64 + lane], p);
        }

        float yv = -ALPHA * p + (1.0f - ALPHA) * y[n * 64 + lane];
        y[n * 64 + lane] = yv;
        s[n * 64 + lane] = (1.0f - ALPHA) * s[n * 64 + lane] + av;
        if (!last) hnxt[n * 64 + lane] = nfn * (yv + xU[n * 64 + lane]);
    }
}

// ---------------------------------------------------------------------------
// FALLBACK: R2's fused step (proven 413 us/step). adj holds other|role<<31.
// ---------------------------------------------------------------------------
__global__ __launch_bounds__(256) void fused_step(
        const int* __restrict__ adj, const int* __restrict__ offs,
        const int* __restrict__ cnt,
        const float* __restrict__ hcur, float* __restrict__ hnxt,
        const float* __restrict__ nf, const float* __restrict__ gamma,
        const float* __restrict__ beta, const float* __restrict__ Gm,
        const float* __restrict__ xU,
        float* __restrict__ y, float* __restrict__ s, int last) {
    __shared__ float Gs[64 * 64];
    for (int t = threadIdx.x; t < 64 * 64; t += 256) Gs[t] = Gm[t];
    __syncthreads();

    int lane = threadIdx.x & 63, wv = threadIdx.x >> 6;
    float g = gamma[lane], b = beta[lane];

    for (int n = blockIdx.x * 4 + wv; n < NN; n += gridDim.x * 4) {
        int base = offs[n], deg = cnt[n];
        float hn = hcur[n * 64 + lane];
        float accM = 0.f;
        int   ncol = 0;

        for (int c = 0; c < deg; c += 64) {
            int rem = deg - c;
            int nv  = rem < 64 ? rem : 64;
            int ev  = 0;
            if (lane < nv) ev = adj[base + c + lane];

            int jj = 0;
            if (nv >= 2) {
                int ea = __builtin_amdgcn_readlane(ev, 0);
                int eb = __builtin_amdgcn_readlane(ev, 1);
                float hoa = hcur[(ea & 0xffff) * 64 + lane];
                float hob = hcur[(eb & 0xffff) * 64 + lane];
                while (jj + 1 < nv) {
                    int j2 = jj + 2;
                    int ea_n = 0, eb_n = 0;
                    float hoa_n = 0.f, hob_n = 0.f;
                    if (j2 + 1 < nv) {
                        ea_n = __builtin_amdgcn_readlane(ev, j2);
                        eb_n = __builtin_amdgcn_readlane(ev, j2 + 1);
                        hoa_n = hcur[(ea_n & 0xffff) * 64 + lane];
                        hob_n = hcur[(eb_n & 0xffff) * 64 + lane];
                    }
                    float da = fast_tanh(hn - hoa);
                    float db = fast_tanh(hn - hob);
                    float ss[4] = {da, db, da * da, db * db};
                    wavesum_bcastN<4>(ss);
                    float mua = ss[0] * 0.015625f;
                    float mub = ss[1] * 0.015625f;
                    float va  = ss[2] * 0.015625f - mua * mua;
                    float vb  = ss[3] * 0.015625f - mub * mub;
                    va = va > 0.f ? va : 0.f;
                    vb = vb > 0.f ? vb : 0.f;
                    float ga = g * __frsqrt_rn(va + LN_EPS);
                    float gb = g * __frsqrt_rn(vb + LN_EPS);
                    accM += ga * (da - mua) + gb * (db - mub) + 2.0f * b;
                    ncol += ((unsigned)ea >> 31) + ((unsigned)eb >> 31);
                    ea = ea_n; eb = eb_n; hoa = hoa_n; hob = hob_n;
                    jj = j2;
                }
            }
            if (jj < nv) {
                int e = __builtin_amdgcn_readlane(ev, jj);
                float ho = hcur[(e & 0xffff) * 64 + lane];
                float d  = fast_tanh(hn - ho);
                float s1 = wavesum_bcast(d);
                float s2 = wavesum_bcast(d * d);
                float mu = s1 * 0.015625f;
                float v  = s2 * 0.015625f - mu * mu;
                v = v > 0.f ? v : 0.f;
                float gr = g * __frsqrt_rn(v + LN_EPS);
                accM += gr * (d - mu) + b;
                ncol += (unsigned)e >> 31;
            }
        }

        float nfn = nf[n];
        float av  = nfn * (accM - 2.0f * b * (float)ncol);

        float p = 0.f;
        int avi = __float_as_int(av);
#pragma unroll
        for (int k = 0; k < 64; ++k) {
            float ak = __int_as_float(__builtin_amdgcn_readlane(avi, k));
            p = __builtin_fmaf(ak, Gs[k * 64 + lane], p);
        }

        float yv = -ALPHA * p + (1.0f - ALPHA) * y[n * 64 + lane];
        y[n * 64 + lane] = yv;
        s[n * 64 + lane] = (1.0f - ALPHA) * s[n * 64 + lane] + av;
        if (!last) hnxt[n * 64 + lane] = nfn * (yv + xU[n * 64 + lane]);
    }
}

// ---------------------------------------------------------------------------
// final: z = -alpha*(s@W) ; zf = nf*z + xh ; out = zf@Wlast^T + blast
// ---------------------------------------------------------------------------
__global__ __launch_bounds__(256) void final_out(
        const float* __restrict__ s, const float* __restrict__ xh,
        const float* __restrict__ nf, const float* __restrict__ W,
        const float* __restrict__ Wlast, const float* __restrict__ blast,
        float* __restrict__ out) {
    __shared__ float Ws[64 * 64];
    __shared__ float WlT[64 * OUTC];
    __shared__ float blS[OUTC];
    __shared__ float ss[4][64];
    __shared__ float zfs[4][64];
    for (int t = threadIdx.x; t < 64 * 64; t += 256) Ws[t] = W[t];
    for (int t = threadIdx.x; t < OUTC * 64; t += 256) {
        int o = t >> 6, j = t & 63;
        WlT[j * OUTC + o] = Wlast[t];
    }
    if (threadIdx.x < OUTC) blS[threadIdx.x] = blast[threadIdx.x];
    __syncthreads();
    int lane = threadIdx.x & 63, wv = threadIdx.x >> 6;
    for (int n0 = blockIdx.x * 4; n0 < NN; n0 += gridDim.x * 4) {
        int n = n0 + wv;
        if (n < NN) ss[wv][lane] = s[n * 64 + lane];
        __syncthreads();
        if (n < NN) {
            float z = 0.f;
#pragma unroll 8
            for (int k = 0; k < 64; ++k) z += ss[wv][k] * Ws[k * 64 + lane];
            z *= -ALPHA;
            zfs[wv][lane] = nf[n] * z + xh[n * 64 + lane];
        }
        __syncthreads();
        if (n < NN && lane < OUTC) {
            float acc = blS[lane];
#pragma unroll 8
            for (int j = 0; j < 64; ++j) acc += zfs[wv][j] * WlT[j * OUTC + lane];
            out[n * OUTC + lane] = acc;
        }
        __syncthreads();
    }
}

// ---------------------------------------------------------------------------
extern "C" void kernel_launch(void* const* d_in, const int* in_sizes, int n_in,
                              void* d_out, int out_size, void* d_ws, size_t ws_size,
                              hipStream_t stream) {
    const float* x     = (const float*)d_in[0];
    const int*   ei    = (const int*)  d_in[1];
    const float* nf    = (const float*)d_in[2];
    const float* We    = (const float*)d_in[3];
    const float* be    = (const float*)d_in[4];
    const float* W     = (const float*)d_in[5];
    const float* U     = (const float*)d_in[6];
    const float* bU    = (const float*)d_in[7];
    const float* gamma = (const float*)d_in[8];
    const float* beta  = (const float*)d_in[9];
    const float* Wlast = (const float*)d_in[10];
    const float* blast = (const float*)d_in[11];
    float* out = (float*)d_out;

    char* ws = (char*)d_ws;
    size_t off = 0;
    const size_t NH = (size_t)NN * HH * sizeof(float);
    int*   adj  = (int*)(ws + off);   off += (size_t)2 * EE * sizeof(int);
    int*   offs = (int*)(ws + off);   off += (size_t)NN * sizeof(int);
    int*   cnt  = (int*)(ws + off);   off += (size_t)NN * sizeof(int);
    int*   cur  = (int*)(ws + off);   off += (size_t)NN * sizeof(int);
    int*   bsum = (int*)(ws + off);   off += 1024 * sizeof(int);
    float* xh   = (float*)(ws + off); off += NH;
    float* xU   = (float*)(ws + off); off += NH;
    float* h0   = (float*)(ws + off); off += NH;
    float* h1   = (float*)(ws + off); off += NH;
    float* y    = (float*)(ws + off); off += NH;
    float* s    = (float*)(ws + off); off += NH;
    float* G    = (float*)(ws + off); off += (size_t)HH * HH * sizeof(float);
    _Float16* m16 = (_Float16*)(ws + off);
    size_t need_fast = off + (size_t)EE * HH * sizeof(_Float16);
    int fast = (ws_size >= need_fast) ? 1 : 0;

    hipMemsetAsync(cnt, 0, (size_t)NN * sizeof(int), stream);
    hipMemsetAsync(y, 0, 2 * NH, stream);   // y and s are adjacent

    // CSR build (once per launch)
    csr_count<<<(2 * EE + 255) / 256, 256, 0, stream>>>(ei, cnt);
    scanA<<<NB_SCAN, 256, 0, stream>>>(cnt, offs, bsum);
    scanB<<<1, 256, 0, stream>>>(bsum);
    scanC<<<NB_SCAN, 256, 0, stream>>>(offs, cur, bsum);
    csr_fill<<<(2 * EE + 255) / 256, 256, 0, stream>>>(ei, cur, adj, fast);

    make_G<<<1, 256, 0, stream>>>(W, G);
    extractor<<<512, 256, 0, stream>>>(x, nf, We, be, U, bU, xh, xU, h0);

    float* hc = h0;
    float* hn = h1;
    if (fast) {
        for (int t = 0; t < 4; ++t) {
            edge_msg<<<2048, 256, 0, stream>>>(ei, hc, gamma, beta, m16);
            gather_update<<<2048, 256, 0, stream>>>(adj, offs, cnt, m16, nf, G,
                                                    xU, y, s, hn, t == 3);
            float* tmp = hc; hc = hn; hn = tmp;
        }
    } else {
        for (int t = 0; t < 4; ++t) {
            fused_step<<<2048, 256, 0, stream>>>(adj, offs, cnt, hc, hn, nf,
                                                 gamma, beta, G, xU, y, s, t == 3);
            float* tmp = hc; hc = hn; hn = tmp;
        }
    }
    final_out<<<512, 256, 0, stream>>>(s, xh, nf, W, Wlast, blast, out);
}

// Round 6
// 1978.968 us; speedup vs baseline: 1.2984x; 1.0883x over previous
//
#include <hip/hip_runtime.h>
#include <hip/hip_bf16.h>

// Problem constants (from reference)
#define NN   50000
#define EE   1600000
#define INC  128
#define HH   64
#define OUTC 40
#define ALPHA 0.8f
#define LN_EPS 1e-5f
#define NB_SCAN 196   // ceil(NN/256)

// ---------------------------------------------------------------------------
// DPP wave64 sum, N independent chains in lock-step. Result broadcast to all
// lanes via readlane(63). VALU pipe only.
// ---------------------------------------------------------------------------
#define DPP_STAGE(CTRL, MASK)                                                  \
    _Pragma("unroll")                                                          \
    for (int _i = 0; _i < N; ++_i) {                                           \
        int _r = __builtin_amdgcn_update_dpp(0, __float_as_int(v[_i]),         \
                                             CTRL, MASK, 0xf, true);           \
        v[_i] += __int_as_float(_r);                                           \
    }

template <int N>
__device__ __forceinline__ void wavesum_bcastN(float* v) {
    DPP_STAGE(0x111, 0xf)   // row_shr:1
    DPP_STAGE(0x112, 0xf)   // row_shr:2
    DPP_STAGE(0x114, 0xf)   // row_shr:4
    DPP_STAGE(0x118, 0xf)   // row_shr:8
    DPP_STAGE(0x142, 0xa)   // row_bcast:15
    DPP_STAGE(0x143, 0xc)   // row_bcast:31 -> lane63 = total
#pragma unroll
    for (int i = 0; i < N; ++i)
        v[i] = __int_as_float(__builtin_amdgcn_readlane(__float_as_int(v[i]), 63));
}

__device__ __forceinline__ float fast_tanh(float x) {
    float e = __builtin_amdgcn_exp2f(-2.8853900817779268f * __builtin_fabsf(x));
    float t = (1.0f - e) * __builtin_amdgcn_rcpf(1.0f + e);
    return __builtin_copysignf(t, x);
}

// ---------------------------------------------------------------------------
// CSR build. ei is [2,E] flat int32. adj stores other-endpoint | role<<31.
// ---------------------------------------------------------------------------
__global__ __launch_bounds__(256) void csr_count(const int* __restrict__ ei,
                                                 int* __restrict__ cnt) {
    int i = blockIdx.x * 256 + threadIdx.x;
    if (i < 2 * EE) atomicAdd(&cnt[ei[i]], 1);
}

__global__ __launch_bounds__(256) void scanA(const int* __restrict__ cnt,
                                             int* __restrict__ offs,
                                             int* __restrict__ bsum) {
    __shared__ int tmp[256];
    int i = blockIdx.x * 256 + threadIdx.x;
    int v = (i < NN) ? cnt[i] : 0;
    tmp[threadIdx.x] = v;
    __syncthreads();
    int acc = v;
    for (int d = 1; d < 256; d <<= 1) {
        int t = (threadIdx.x >= d) ? tmp[threadIdx.x - d] : 0;
        __syncthreads();
        acc += t;
        tmp[threadIdx.x] = acc;
        __syncthreads();
    }
    if (i < NN) offs[i] = acc - v;
    if (threadIdx.x == 255) bsum[blockIdx.x] = acc;
}

__global__ __launch_bounds__(256) void scanB(int* __restrict__ bsum) {
    __shared__ int tmp[256];
    int v = (threadIdx.x < NB_SCAN) ? bsum[threadIdx.x] : 0;
    tmp[threadIdx.x] = v;
    __syncthreads();
    int acc = v;
    for (int d = 1; d < 256; d <<= 1) {
        int t = (threadIdx.x >= d) ? tmp[threadIdx.x - d] : 0;
        __syncthreads();
        acc += t;
        tmp[threadIdx.x] = acc;
        __syncthreads();
    }
    if (threadIdx.x < NB_SCAN) bsum[threadIdx.x] = acc - v;
}

__global__ __launch_bounds__(256) void scanC(int* __restrict__ offs,
                                             int* __restrict__ cur,
                                             const int* __restrict__ bsum) {
    int i = blockIdx.x * 256 + threadIdx.x;
    if (i < NN) {
        int o = offs[i] + bsum[blockIdx.x];
        offs[i] = o;
        cur[i]  = o;
    }
}

__global__ __launch_bounds__(256) void csr_fill(const int* __restrict__ ei,
                                                int* __restrict__ cur,
                                                int* __restrict__ adj) {
    int i = blockIdx.x * 256 + threadIdx.x;
    if (i >= 2 * EE) return;
    int node  = ei[i];
    int role  = (i >= EE) ? 1 : 0;
    int other = role ? ei[i - EE] : ei[i + EE];
    int p = atomicAdd(&cur[node], 1);
    adj[p] = other | (role << 31);
}

// ---------------------------------------------------------------------------
// G = W @ W^T  (64x64). One block.
// ---------------------------------------------------------------------------
__global__ __launch_bounds__(256) void make_G(const float* __restrict__ W,
                                              float* __restrict__ G) {
    __shared__ float Ws[64 * 64];
    for (int t = threadIdx.x; t < 64 * 64; t += 256) Ws[t] = W[t];
    __syncthreads();
    for (int t = threadIdx.x; t < 64 * 64; t += 256) {
        int i = t >> 6, j = t & 63;
        float acc = 0.f;
#pragma unroll 8
        for (int k = 0; k < 64; ++k) acc += Ws[i * 64 + k] * Ws[j * 64 + k];
        G[t] = acc;
    }
}

// ---------------------------------------------------------------------------
// extractor: xh = x@We^T + be ; h0 = xh@U^T + bU ; xU = h0 / nf
// ---------------------------------------------------------------------------
__global__ __launch_bounds__(256) void extractor(
        const float* __restrict__ x, const float* __restrict__ nf,
        const float* __restrict__ We, const float* __restrict__ be,
        const float* __restrict__ U,  const float* __restrict__ bU,
        float* __restrict__ xh, float* __restrict__ xU, float* __restrict__ h0) {
    __shared__ float WeT[INC * HH];
    __shared__ float UT[HH * HH];
    __shared__ float beS[HH], bUS[HH];
    __shared__ float xs[4][INC];
    __shared__ float xhs[4][HH];

    for (int t = threadIdx.x; t < INC * HH; t += 256) {
        int j = t >> 7, k = t & 127;
        WeT[k * 64 + j] = We[t];
    }
    for (int t = threadIdx.x; t < HH * HH; t += 256) {
        int j = t >> 6, k = t & 63;
        UT[k * 64 + j] = U[t];
    }
    if (threadIdx.x < 64) { beS[threadIdx.x] = be[threadIdx.x]; bUS[threadIdx.x] = bU[threadIdx.x]; }
    __syncthreads();

    int lane = threadIdx.x & 63;
    int wv   = threadIdx.x >> 6;

    for (int n0 = blockIdx.x * 4; n0 < NN; n0 += gridDim.x * 4) {
        int n = n0 + wv;
        bool valid = n < NN;
        if (valid) {
            xs[wv][lane]      = x[(size_t)n * INC + lane];
            xs[wv][lane + 64] = x[(size_t)n * INC + lane + 64];
        }
        __syncthreads();
        float acc = beS[lane];
        if (valid) {
#pragma unroll 8
            for (int k = 0; k < INC; ++k) acc += xs[wv][k] * WeT[k * 64 + lane];
            xh[n * 64 + lane] = acc;
            xhs[wv][lane] = acc;
        }
        __syncthreads();
        if (valid) {
            float acc2 = bUS[lane];
#pragma unroll 8
            for (int k = 0; k < HH; ++k) acc2 += xhs[wv][k] * UT[k * 64 + lane];
            h0[n * 64 + lane] = acc2;
            xU[n * 64 + lane] = acc2 / nf[n];
        }
        __syncthreads();
    }
}

// ---------------------------------------------------------------------------
// fused step v3: per node n (one wave, lane = channel).
// Branchless quad inner loop: 4 edges/iter, 8 lock-step DPP chains, scalar
// (SGPR) h-row addressing. Tail edges are clamped duplicates, zeroed via a
// single cndmask on rsig. Per node:
//   accM = sum_e rsig_e*(d_e - mu_e)   (gamma hoisted)
//   sigma = deg - 2*ncol               (beta hoisted; exact via ballot mask)
//   a = nf*(g*accM + b*sigma) ; p = a@G ; y,s,h updates. No atomics.
// ---------------------------------------------------------------------------
__global__ __launch_bounds__(256) void fused_step(
        const int* __restrict__ adj, const int* __restrict__ offs,
        const int* __restrict__ cnt,
        const float* __restrict__ hcur, float* __restrict__ hnxt,
        const float* __restrict__ nf, const float* __restrict__ gamma,
        const float* __restrict__ beta, const float* __restrict__ Gm,
        const float* __restrict__ xU,
        float* __restrict__ y, float* __restrict__ s, int last) {
    __shared__ float Gs[64 * 64];
    for (int t = threadIdx.x; t < 64 * 64; t += 256) Gs[t] = Gm[t];
    __syncthreads();

    const int lane = threadIdx.x & 63, wv = threadIdx.x >> 6;
    const float g = gamma[lane], b = beta[lane];

    for (int n = blockIdx.x * 4 + wv; n < NN; n += gridDim.x * 4) {
        const int base = offs[n], deg = cnt[n];
        const float hn = hcur[n * 64 + lane];
        float accM = 0.f;
        int sigma = 0;                       // deg - 2*ncol, accumulated

        for (int c = 0; c < deg; c += 64) {
            int nv = deg - c; nv = nv < 64 ? nv : 64;
            int li = lane < nv ? lane : nv - 1;          // clamp load index
            int ev = adj[base + c + li];
            unsigned long long bal = __ballot(ev < 0);
            unsigned long long msk =
                (nv >= 64) ? ~0ull : ((1ull << nv) - 1ull);
            sigma += nv - 2 * __builtin_popcountll(bal & msk);

            const int quads = (nv + 3) >> 2;
            for (int q = 0; q < quads; ++q) {
                const int j0 = q << 2;
                float d[4], ss[8];
#pragma unroll
                for (int i = 0; i < 4; ++i) {
                    int ji = j0 + i;
                    ji = ji < nv ? ji : nv - 1;          // uniform clamp
                    int e = __builtin_amdgcn_readlane(ev, ji);
                    const float* hp =
                        hcur + (size_t)((unsigned)e & 0x7fffffffu) * 64u;
                    float dd = fast_tanh(hn - hp[lane]);
                    d[i] = dd;
                    ss[i] = dd;
                    ss[i + 4] = dd * dd;
                }
                wavesum_bcastN<8>(ss);
#pragma unroll
                for (int i = 0; i < 4; ++i) {
                    float mu  = ss[i] * 0.015625f;
                    float var = __builtin_fmaf(ss[i + 4], 0.015625f, -mu * mu);
                    var = var > 0.f ? var : 0.f;
                    float rsig = __frsqrt_rn(var + LN_EPS);
                    rsig = (j0 + i < nv) ? rsig : 0.f;   // kill tail dupes
                    accM = __builtin_fmaf(rsig, d[i] - mu, accM);
                }
            }
        }

        const float nfn = nf[n];
        const float av  = nfn * __builtin_fmaf(g, accM, b * (float)sigma);

        // p[lane] = sum_k av(lane k) * G[k][lane] via readlane broadcast
        float p = 0.f;
        const int avi = __float_as_int(av);
#pragma unroll
        for (int k = 0; k < 64; ++k) {
            float ak = __int_as_float(__builtin_amdgcn_readlane(avi, k));
            p = __builtin_fmaf(ak, Gs[k * 64 + lane], p);
        }

        const float yv = -ALPHA * p + (1.0f - ALPHA) * y[n * 64 + lane];
        y[n * 64 + lane] = yv;
        s[n * 64 + lane] = (1.0f - ALPHA) * s[n * 64 + lane] + av;
        if (!last) hnxt[n * 64 + lane] = nfn * (yv + xU[n * 64 + lane]);
    }
}

// ---------------------------------------------------------------------------
// final: z = -alpha*(s@W) ; zf = nf*z + xh ; out = zf@Wlast^T + blast
// ---------------------------------------------------------------------------
__global__ __launch_bounds__(256) void final_out(
        const float* __restrict__ s, const float* __restrict__ xh,
        const float* __restrict__ nf, const float* __restrict__ W,
        const float* __restrict__ Wlast, const float* __restrict__ blast,
        float* __restrict__ out) {
    __shared__ float Ws[64 * 64];
    __shared__ float WlT[64 * OUTC];
    __shared__ float blS[OUTC];
    __shared__ float ss[4][64];
    __shared__ float zfs[4][64];
    for (int t = threadIdx.x; t < 64 * 64; t += 256) Ws[t] = W[t];
    for (int t = threadIdx.x; t < OUTC * 64; t += 256) {
        int o = t >> 6, j = t & 63;
        WlT[j * OUTC + o] = Wlast[t];
    }
    if (threadIdx.x < OUTC) blS[threadIdx.x] = blast[threadIdx.x];
    __syncthreads();
    int lane = threadIdx.x & 63, wv = threadIdx.x >> 6;
    for (int n0 = blockIdx.x * 4; n0 < NN; n0 += gridDim.x * 4) {
        int n = n0 + wv;
        if (n < NN) ss[wv][lane] = s[n * 64 + lane];
        __syncthreads();
        if (n < NN) {
            float z = 0.f;
#pragma unroll 8
            for (int k = 0; k < 64; ++k) z += ss[wv][k] * Ws[k * 64 + lane];
            z *= -ALPHA;
            zfs[wv][lane] = nf[n] * z + xh[n * 64 + lane];
        }
        __syncthreads();
        if (n < NN && lane < OUTC) {
            float acc = blS[lane];
#pragma unroll 8
            for (int j = 0; j < 64; ++j) acc += zfs[wv][j] * WlT[j * OUTC + lane];
            out[n * OUTC + lane] = acc;
        }
        __syncthreads();
    }
}

// ---------------------------------------------------------------------------
extern "C" void kernel_launch(void* const* d_in, const int* in_sizes, int n_in,
                              void* d_out, int out_size, void* d_ws, size_t ws_size,
                              hipStream_t stream) {
    const float* x     = (const float*)d_in[0];
    const int*   ei    = (const int*)  d_in[1];
    const float* nf    = (const float*)d_in[2];
    const float* We    = (const float*)d_in[3];
    const float* be    = (const float*)d_in[4];
    const float* W     = (const float*)d_in[5];
    const float* U     = (const float*)d_in[6];
    const float* bU    = (const float*)d_in[7];
    const float* gamma = (const float*)d_in[8];
    const float* beta  = (const float*)d_in[9];
    const float* Wlast = (const float*)d_in[10];
    const float* blast = (const float*)d_in[11];
    float* out = (float*)d_out;

    char* ws = (char*)d_ws;
    size_t off = 0;
    const size_t NH = (size_t)NN * HH * sizeof(float);
    int*   adj  = (int*)(ws + off);   off += (size_t)2 * EE * sizeof(int);
    int*   offs = (int*)(ws + off);   off += (size_t)NN * sizeof(int);
    int*   cnt  = (int*)(ws + off);   off += (size_t)NN * sizeof(int);
    int*   cur  = (int*)(ws + off);   off += (size_t)NN * sizeof(int);
    int*   bsum = (int*)(ws + off);   off += 256 * sizeof(int);
    float* xh   = (float*)(ws + off); off += NH;
    float* xU   = (float*)(ws + off); off += NH;
    float* h0   = (float*)(ws + off); off += NH;
    float* h1   = (float*)(ws + off); off += NH;
    float* y    = (float*)(ws + off); off += NH;
    float* s    = (float*)(ws + off); off += NH;
    float* G    = (float*)(ws + off); off += (size_t)HH * HH * sizeof(float);

    hipMemsetAsync(cnt, 0, (size_t)NN * sizeof(int), stream);
    hipMemsetAsync(y, 0, 2 * NH, stream);   // y and s are adjacent

    // CSR build (once per launch)
    csr_count<<<(2 * EE + 255) / 256, 256, 0, stream>>>(ei, cnt);
    scanA<<<NB_SCAN, 256, 0, stream>>>(cnt, offs, bsum);
    scanB<<<1, 256, 0, stream>>>(bsum);
    scanC<<<NB_SCAN, 256, 0, stream>>>(offs, cur, bsum);
    csr_fill<<<(2 * EE + 255) / 256, 256, 0, stream>>>(ei, cur, adj);

    make_G<<<1, 256, 0, stream>>>(W, G);
    extractor<<<512, 256, 0, stream>>>(x, nf, We, be, U, bU, xh, xU, h0);

    float* hc = h0;
    float* hn = h1;
    for (int t = 0; t < 4; ++t) {
        fused_step<<<2048, 256, 0, stream>>>(adj, offs, cnt, hc, hn, nf,
                                             gamma, beta, G, xU, y, s, t == 3);
        float* tmp = hc; hc = hn; hn = tmp;
    }
    final_out<<<512, 256, 0, stream>>>(s, xh, nf, W, Wlast, blast, out);
}

// Round 7
// 1788.052 us; speedup vs baseline: 1.4370x; 1.1068x over previous
//
#include <hip/hip_runtime.h>
#include <hip/hip_bf16.h>

// Problem constants (from reference)
#define NN   50000
#define EE   1600000
#define INC  128
#define HH   64
#define OUTC 40
#define ALPHA 0.8f
#define LN_EPS 1e-5f
#define NB_SCAN 196   // ceil(NN/256)

// ---------------------------------------------------------------------------
// Wave64 sum via fused v_add_f32_dpp (inline asm; 1 inst/stage guaranteed).
// 8 independent chains interleaved: dependent ops are 8 insts apart, which
// also satisfies DPP wait-state requirements. Total lands in lane 63.
// ---------------------------------------------------------------------------
#define DPP8(CTRL)                                                             \
    asm volatile(                                                              \
        "v_add_f32_dpp %0, %0, %0 " CTRL "\n\t"                                \
        "v_add_f32_dpp %1, %1, %1 " CTRL "\n\t"                                \
        "v_add_f32_dpp %2, %2, %2 " CTRL "\n\t"                                \
        "v_add_f32_dpp %3, %3, %3 " CTRL "\n\t"                                \
        "v_add_f32_dpp %4, %4, %4 " CTRL "\n\t"                                \
        "v_add_f32_dpp %5, %5, %5 " CTRL "\n\t"                                \
        "v_add_f32_dpp %6, %6, %6 " CTRL "\n\t"                                \
        "v_add_f32_dpp %7, %7, %7 " CTRL                                       \
        : "+v"(s0), "+v"(s1), "+v"(s2), "+v"(s3),                              \
          "+v"(s4), "+v"(s5), "+v"(s6), "+v"(s7))

__device__ __forceinline__ float rl63(float x) {
    return __int_as_float(__builtin_amdgcn_readlane(__float_as_int(x), 63));
}

__device__ __forceinline__ float fast_tanh(float x) {
    float e = __builtin_amdgcn_exp2f(-2.8853900817779268f * __builtin_fabsf(x));
    float t = (1.0f - e) * __builtin_amdgcn_rcpf(1.0f + e);
    return __builtin_copysignf(t, x);
}

// single-chain wave sum (scanB helper not needed; kept minimal)

// ---------------------------------------------------------------------------
// CSR build. ei is [2,E] flat int32. adj stores other-endpoint | role<<31.
// ---------------------------------------------------------------------------
__global__ __launch_bounds__(256) void csr_count(const int* __restrict__ ei,
                                                 int* __restrict__ cnt) {
    int i = blockIdx.x * 256 + threadIdx.x;
    if (i < 2 * EE) atomicAdd(&cnt[ei[i]], 1);
}

__global__ __launch_bounds__(256) void scanA(const int* __restrict__ cnt,
                                             int* __restrict__ offs,
                                             int* __restrict__ bsum) {
    __shared__ int tmp[256];
    int i = blockIdx.x * 256 + threadIdx.x;
    int v = (i < NN) ? cnt[i] : 0;
    tmp[threadIdx.x] = v;
    __syncthreads();
    int acc = v;
    for (int d = 1; d < 256; d <<= 1) {
        int t = (threadIdx.x >= d) ? tmp[threadIdx.x - d] : 0;
        __syncthreads();
        acc += t;
        tmp[threadIdx.x] = acc;
        __syncthreads();
    }
    if (i < NN) offs[i] = acc - v;
    if (threadIdx.x == 255) bsum[blockIdx.x] = acc;
}

__global__ __launch_bounds__(256) void scanB(int* __restrict__ bsum) {
    __shared__ int tmp[256];
    int v = (threadIdx.x < NB_SCAN) ? bsum[threadIdx.x] : 0;
    tmp[threadIdx.x] = v;
    __syncthreads();
    int acc = v;
    for (int d = 1; d < 256; d <<= 1) {
        int t = (threadIdx.x >= d) ? tmp[threadIdx.x - d] : 0;
        __syncthreads();
        acc += t;
        tmp[threadIdx.x] = acc;
        __syncthreads();
    }
    if (threadIdx.x < NB_SCAN) bsum[threadIdx.x] = acc - v;
}

__global__ __launch_bounds__(256) void scanC(int* __restrict__ offs,
                                             int* __restrict__ cur,
                                             const int* __restrict__ bsum) {
    int i = blockIdx.x * 256 + threadIdx.x;
    if (i < NN) {
        int o = offs[i] + bsum[blockIdx.x];
        offs[i] = o;
        cur[i]  = o;
    }
}

__global__ __launch_bounds__(256) void csr_fill(const int* __restrict__ ei,
                                                int* __restrict__ cur,
                                                int* __restrict__ adj) {
    int i = blockIdx.x * 256 + threadIdx.x;
    if (i >= 2 * EE) return;
    int node  = ei[i];
    int role  = (i >= EE) ? 1 : 0;
    int other = role ? ei[i - EE] : ei[i + EE];
    int p = atomicAdd(&cur[node], 1);
    adj[p] = other | (role << 31);
}

// ---------------------------------------------------------------------------
// G = W @ W^T  (64x64). One block.
// ---------------------------------------------------------------------------
__global__ __launch_bounds__(256) void make_G(const float* __restrict__ W,
                                              float* __restrict__ G) {
    __shared__ float Ws[64 * 64];
    for (int t = threadIdx.x; t < 64 * 64; t += 256) Ws[t] = W[t];
    __syncthreads();
    for (int t = threadIdx.x; t < 64 * 64; t += 256) {
        int i = t >> 6, j = t & 63;
        float acc = 0.f;
#pragma unroll 8
        for (int k = 0; k < 64; ++k) acc += Ws[i * 64 + k] * Ws[j * 64 + k];
        G[t] = acc;
    }
}

// ---------------------------------------------------------------------------
// extractor: xh = x@We^T + be ; h0 = xh@U^T + bU ; xU = h0 / nf
// ---------------------------------------------------------------------------
__global__ __launch_bounds__(256) void extractor(
        const float* __restrict__ x, const float* __restrict__ nf,
        const float* __restrict__ We, const float* __restrict__ be,
        const float* __restrict__ U,  const float* __restrict__ bU,
        float* __restrict__ xh, float* __restrict__ xU, float* __restrict__ h0) {
    __shared__ float WeT[INC * HH];
    __shared__ float UT[HH * HH];
    __shared__ float beS[HH], bUS[HH];
    __shared__ float xs[4][INC];
    __shared__ float xhs[4][HH];

    for (int t = threadIdx.x; t < INC * HH; t += 256) {
        int j = t >> 7, k = t & 127;
        WeT[k * 64 + j] = We[t];
    }
    for (int t = threadIdx.x; t < HH * HH; t += 256) {
        int j = t >> 6, k = t & 63;
        UT[k * 64 + j] = U[t];
    }
    if (threadIdx.x < 64) { beS[threadIdx.x] = be[threadIdx.x]; bUS[threadIdx.x] = bU[threadIdx.x]; }
    __syncthreads();

    int lane = threadIdx.x & 63;
    int wv   = threadIdx.x >> 6;

    for (int n0 = blockIdx.x * 4; n0 < NN; n0 += gridDim.x * 4) {
        int n = n0 + wv;
        bool valid = n < NN;
        if (valid) {
            xs[wv][lane]      = x[(size_t)n * INC + lane];
            xs[wv][lane + 64] = x[(size_t)n * INC + lane + 64];
        }
        __syncthreads();
        float acc = beS[lane];
        if (valid) {
#pragma unroll 8
            for (int k = 0; k < INC; ++k) acc += xs[wv][k] * WeT[k * 64 + lane];
            xh[n * 64 + lane] = acc;
            xhs[wv][lane] = acc;
        }
        __syncthreads();
        if (valid) {
            float acc2 = bUS[lane];
#pragma unroll 8
            for (int k = 0; k < HH; ++k) acc2 += xhs[wv][k] * UT[k * 64 + lane];
            h0[n * 64 + lane] = acc2;
            xU[n * 64 + lane] = acc2 / nf[n];
        }
        __syncthreads();
    }
}

// ---------------------------------------------------------------------------
// fused step v4: per node n (one wave, lane = channel).
// Quad inner loop with one-quad-ahead clamped prefetch; 8 lock-step
// reduction chains as fused v_add_f32_dpp (inline asm). Per node:
//   accM  = sum_e rsig_e*(d_e - mu_e)     (gamma hoisted)
//   sigma = deg - 2*ncol                  (beta hoisted; exact via ballot)
//   a = nf*(g*accM + b*sigma) ; p = a@G ; y,s,h updates. No atomics.
// ---------------------------------------------------------------------------
__global__ __launch_bounds__(256) void fused_step(
        const int* __restrict__ adj, const int* __restrict__ offs,
        const int* __restrict__ cnt,
        const float* __restrict__ hcur, float* __restrict__ hnxt,
        const float* __restrict__ nf, const float* __restrict__ gamma,
        const float* __restrict__ beta, const float* __restrict__ Gm,
        const float* __restrict__ xU,
        float* __restrict__ y, float* __restrict__ s, int last) {
    __shared__ float Gs[64 * 64];
    for (int t = threadIdx.x; t < 64 * 64; t += 256) Gs[t] = Gm[t];
    __syncthreads();

    const int lane = threadIdx.x & 63, wv = threadIdx.x >> 6;
    const float g = gamma[lane], b = beta[lane];

    for (int n = blockIdx.x * 4 + wv; n < NN; n += gridDim.x * 4) {
        const int base = offs[n], deg = cnt[n];
        const float hn = hcur[n * 64 + lane];
        float accM = 0.f;
        int sigma = 0;

        for (int c = 0; c < deg; c += 64) {
            int nv = deg - c; nv = nv < 64 ? nv : 64;
            int li = lane < nv ? lane : nv - 1;
            int ev = adj[base + c + li];
            unsigned long long bal = __ballot(ev < 0);
            unsigned long long msk = (nv >= 64) ? ~0ull : ((1ull << nv) - 1ull);
            sigma += nv - 2 * __builtin_popcountll(bal & msk);

            // prefetch quad 0 (clamped, branchless)
            float hv0, hv1, hv2, hv3;
            {
                int j0c = 0;
                int j1c = 1 < nv ? 1 : nv - 1;
                int j2c = 2 < nv ? 2 : nv - 1;
                int j3c = 3 < nv ? 3 : nv - 1;
                int e0 = __builtin_amdgcn_readlane(ev, j0c);
                int e1 = __builtin_amdgcn_readlane(ev, j1c);
                int e2 = __builtin_amdgcn_readlane(ev, j2c);
                int e3 = __builtin_amdgcn_readlane(ev, j3c);
                hv0 = hcur[(size_t)((unsigned)e0 & 0x7fffffffu) * 64u + lane];
                hv1 = hcur[(size_t)((unsigned)e1 & 0x7fffffffu) * 64u + lane];
                hv2 = hcur[(size_t)((unsigned)e2 & 0x7fffffffu) * 64u + lane];
                hv3 = hcur[(size_t)((unsigned)e3 & 0x7fffffffu) * 64u + lane];
            }

            const int quads = (nv + 3) >> 2;
            for (int q = 0; q < quads; ++q) {
                const int j0 = q << 2;
                // prefetch next quad (clamped; harmless dup loads at tail)
                float hn0, hn1, hn2, hn3;
                {
                    int ja = j0 + 4; ja = ja < nv ? ja : nv - 1;
                    int jb = j0 + 5; jb = jb < nv ? jb : nv - 1;
                    int jc = j0 + 6; jc = jc < nv ? jc : nv - 1;
                    int jd = j0 + 7; jd = jd < nv ? jd : nv - 1;
                    int e0 = __builtin_amdgcn_readlane(ev, ja);
                    int e1 = __builtin_amdgcn_readlane(ev, jb);
                    int e2 = __builtin_amdgcn_readlane(ev, jc);
                    int e3 = __builtin_amdgcn_readlane(ev, jd);
                    hn0 = hcur[(size_t)((unsigned)e0 & 0x7fffffffu) * 64u + lane];
                    hn1 = hcur[(size_t)((unsigned)e1 & 0x7fffffffu) * 64u + lane];
                    hn2 = hcur[(size_t)((unsigned)e2 & 0x7fffffffu) * 64u + lane];
                    hn3 = hcur[(size_t)((unsigned)e3 & 0x7fffffffu) * 64u + lane];
                }

                float d0 = fast_tanh(hn - hv0);
                float d1 = fast_tanh(hn - hv1);
                float d2 = fast_tanh(hn - hv2);
                float d3 = fast_tanh(hn - hv3);
                float s0 = d0, s1 = d1, s2 = d2, s3 = d3;
                float s4 = d0 * d0, s5 = d1 * d1, s6 = d2 * d2, s7 = d3 * d3;

                DPP8("row_shr:1 row_mask:0xf bank_mask:0xf bound_ctrl:0");
                DPP8("row_shr:2 row_mask:0xf bank_mask:0xf bound_ctrl:0");
                DPP8("row_shr:4 row_mask:0xf bank_mask:0xf bound_ctrl:0");
                DPP8("row_shr:8 row_mask:0xf bank_mask:0xf bound_ctrl:0");
                DPP8("row_bcast:15 row_mask:0xa bank_mask:0xf bound_ctrl:0");
                DPP8("row_bcast:31 row_mask:0xc bank_mask:0xf bound_ctrl:0");

                float t10 = rl63(s0), t11 = rl63(s1), t12 = rl63(s2), t13 = rl63(s3);
                float t20 = rl63(s4), t21 = rl63(s5), t22 = rl63(s6), t23 = rl63(s7);

                float mu, var, rsig;
                mu = t10 * 0.015625f;
                var = __builtin_fmaf(t20, 0.015625f, -mu * mu);
                var = var > 0.f ? var : 0.f;
                rsig = __frsqrt_rn(var + LN_EPS);
                rsig = (j0 + 0 < nv) ? rsig : 0.f;
                accM = __builtin_fmaf(rsig, d0 - mu, accM);

                mu = t11 * 0.015625f;
                var = __builtin_fmaf(t21, 0.015625f, -mu * mu);
                var = var > 0.f ? var : 0.f;
                rsig = __frsqrt_rn(var + LN_EPS);
                rsig = (j0 + 1 < nv) ? rsig : 0.f;
                accM = __builtin_fmaf(rsig, d1 - mu, accM);

                mu = t12 * 0.015625f;
                var = __builtin_fmaf(t22, 0.015625f, -mu * mu);
                var = var > 0.f ? var : 0.f;
                rsig = __frsqrt_rn(var + LN_EPS);
                rsig = (j0 + 2 < nv) ? rsig : 0.f;
                accM = __builtin_fmaf(rsig, d2 - mu, accM);

                mu = t13 * 0.015625f;
                var = __builtin_fmaf(t23, 0.015625f, -mu * mu);
                var = var > 0.f ? var : 0.f;
                rsig = __frsqrt_rn(var + LN_EPS);
                rsig = (j0 + 3 < nv) ? rsig : 0.f;
                accM = __builtin_fmaf(rsig, d3 - mu, accM);

                hv0 = hn0; hv1 = hn1; hv2 = hn2; hv3 = hn3;
            }
        }

        const float nfn = nf[n];
        const float av  = nfn * __builtin_fmaf(g, accM, b * (float)sigma);

        // p[lane] = sum_k av(lane k) * G[k][lane] via readlane broadcast
        float p = 0.f;
        const int avi = __float_as_int(av);
#pragma unroll
        for (int k = 0; k < 64; ++k) {
            float ak = __int_as_float(__builtin_amdgcn_readlane(avi, k));
            p = __builtin_fmaf(ak, Gs[k * 64 + lane], p);
        }

        const float yv = -ALPHA * p + (1.0f - ALPHA) * y[n * 64 + lane];
        y[n * 64 + lane] = yv;
        s[n * 64 + lane] = (1.0f - ALPHA) * s[n * 64 + lane] + av;
        if (!last) hnxt[n * 64 + lane] = nfn * (yv + xU[n * 64 + lane]);
    }
}

// ---------------------------------------------------------------------------
// final: z = -alpha*(s@W) ; zf = nf*z + xh ; out = zf@Wlast^T + blast
// ---------------------------------------------------------------------------
__global__ __launch_bounds__(256) void final_out(
        const float* __restrict__ s, const float* __restrict__ xh,
        const float* __restrict__ nf, const float* __restrict__ W,
        const float* __restrict__ Wlast, const float* __restrict__ blast,
        float* __restrict__ out) {
    __shared__ float Ws[64 * 64];
    __shared__ float WlT[64 * OUTC];
    __shared__ float blS[OUTC];
    __shared__ float ss[4][64];
    __shared__ float zfs[4][64];
    for (int t = threadIdx.x; t < 64 * 64; t += 256) Ws[t] = W[t];
    for (int t = threadIdx.x; t < OUTC * 64; t += 256) {
        int o = t >> 6, j = t & 63;
        WlT[j * OUTC + o] = Wlast[t];
    }
    if (threadIdx.x < OUTC) blS[threadIdx.x] = blast[threadIdx.x];
    __syncthreads();
    int lane = threadIdx.x & 63, wv = threadIdx.x >> 6;
    for (int n0 = blockIdx.x * 4; n0 < NN; n0 += gridDim.x * 4) {
        int n = n0 + wv;
        if (n < NN) ss[wv][lane] = s[n * 64 + lane];
        __syncthreads();
        if (n < NN) {
            float z = 0.f;
#pragma unroll 8
            for (int k = 0; k < 64; ++k) z += ss[wv][k] * Ws[k * 64 + lane];
            z *= -ALPHA;
            zfs[wv][lane] = nf[n] * z + xh[n * 64 + lane];
        }
        __syncthreads();
        if (n < NN && lane < OUTC) {
            float acc = blS[lane];
#pragma unroll 8
            for (int j = 0; j < 64; ++j) acc += zfs[wv][j] * WlT[j * OUTC + lane];
            out[n * OUTC + lane] = acc;
        }
        __syncthreads();
    }
}

// ---------------------------------------------------------------------------
extern "C" void kernel_launch(void* const* d_in, const int* in_sizes, int n_in,
                              void* d_out, int out_size, void* d_ws, size_t ws_size,
                              hipStream_t stream) {
    const float* x     = (const float*)d_in[0];
    const int*   ei    = (const int*)  d_in[1];
    const float* nf    = (const float*)d_in[2];
    const float* We    = (const float*)d_in[3];
    const float* be    = (const float*)d_in[4];
    const float* W     = (const float*)d_in[5];
    const float* U     = (const float*)d_in[6];
    const float* bU    = (const float*)d_in[7];
    const float* gamma = (const float*)d_in[8];
    const float* beta  = (const float*)d_in[9];
    const float* Wlast = (const float*)d_in[10];
    const float* blast = (const float*)d_in[11];
    float* out = (float*)d_out;

    char* ws = (char*)d_ws;
    size_t off = 0;
    const size_t NH = (size_t)NN * HH * sizeof(float);
    int*   adj  = (int*)(ws + off);   off += (size_t)2 * EE * sizeof(int);
    int*   offs = (int*)(ws + off);   off += (size_t)NN * sizeof(int);
    int*   cnt  = (int*)(ws + off);   off += (size_t)NN * sizeof(int);
    int*   cur  = (int*)(ws + off);   off += (size_t)NN * sizeof(int);
    int*   bsum = (int*)(ws + off);   off += 256 * sizeof(int);
    float* xh   = (float*)(ws + off); off += NH;
    float* xU   = (float*)(ws + off); off += NH;
    float* h0   = (float*)(ws + off); off += NH;
    float* h1   = (float*)(ws + off); off += NH;
    float* y    = (float*)(ws + off); off += NH;
    float* s    = (float*)(ws + off); off += NH;
    float* G    = (float*)(ws + off); off += (size_t)HH * HH * sizeof(float);

    hipMemsetAsync(cnt, 0, (size_t)NN * sizeof(int), stream);
    hipMemsetAsync(y, 0, 2 * NH, stream);   // y and s are adjacent

    // CSR build (once per launch)
    csr_count<<<(2 * EE + 255) / 256, 256, 0, stream>>>(ei, cnt);
    scanA<<<NB_SCAN, 256, 0, stream>>>(cnt, offs, bsum);
    scanB<<<1, 256, 0, stream>>>(bsum);
    scanC<<<NB_SCAN, 256, 0, stream>>>(offs, cur, bsum);
    csr_fill<<<(2 * EE + 255) / 256, 256, 0, stream>>>(ei, cur, adj);

    make_G<<<1, 256, 0, stream>>>(W, G);
    extractor<<<2048, 256, 0, stream>>>(x, nf, We, be, U, bU, xh, xU, h0);

    float* hc = h0;
    float* hn = h1;
    for (int t = 0; t < 4; ++t) {
        fused_step<<<2048, 256, 0, stream>>>(adj, offs, cnt, hc, hn, nf,
                                             gamma, beta, G, xU, y, s, t == 3);
        float* tmp = hc; hc = hn; hn = tmp;
    }
    final_out<<<2048, 256, 0, stream>>>(s, xh, nf, W, Wlast, blast, out);
}

// Round 9
// 1787.251 us; speedup vs baseline: 1.4376x; 1.0004x over previous
//
#include <hip/hip_runtime.h>
#include <hip/hip_bf16.h>

// Problem constants (from reference)
#define NN   50000
#define EE   1600000
#define EH   (EE / 2)          // 800000, % 64 == 0
#define INC  128
#define HH   64
#define OUTC 40
#define ALPHA 0.8f
#define LN_EPS 1e-5f
#define NB_SCAN 196   // ceil(NN/256)
#define QSCALE 4096.0f
#define QINV   (1.0f / 4096.0f)

// ---------------------------------------------------------------------------
// Wave64 sum via fused v_add_f32_dpp (inline asm; 1 inst/stage guaranteed).
// 8 independent chains interleaved (also satisfies DPP wait-states).
// Total lands in lane 63.
// ---------------------------------------------------------------------------
#define DPP8(CTRL)                                                             \
    asm volatile(                                                              \
        "v_add_f32_dpp %0, %0, %0 " CTRL "\n\t"                                \
        "v_add_f32_dpp %1, %1, %1 " CTRL "\n\t"                                \
        "v_add_f32_dpp %2, %2, %2 " CTRL "\n\t"                                \
        "v_add_f32_dpp %3, %3, %3 " CTRL "\n\t"                                \
        "v_add_f32_dpp %4, %4, %4 " CTRL "\n\t"                                \
        "v_add_f32_dpp %5, %5, %5 " CTRL "\n\t"                                \
        "v_add_f32_dpp %6, %6, %6 " CTRL "\n\t"                                \
        "v_add_f32_dpp %7, %7, %7 " CTRL                                       \
        : "+v"(s0), "+v"(s1), "+v"(s2), "+v"(s3),                              \
          "+v"(s4), "+v"(s5), "+v"(s6), "+v"(s7))

#define DPP_ALL6()                                                             \
    DPP8("row_shr:1 row_mask:0xf bank_mask:0xf bound_ctrl:0");                 \
    DPP8("row_shr:2 row_mask:0xf bank_mask:0xf bound_ctrl:0");                 \
    DPP8("row_shr:4 row_mask:0xf bank_mask:0xf bound_ctrl:0");                 \
    DPP8("row_shr:8 row_mask:0xf bank_mask:0xf bound_ctrl:0");                 \
    DPP8("row_bcast:15 row_mask:0xa bank_mask:0xf bound_ctrl:0");              \
    DPP8("row_bcast:31 row_mask:0xc bank_mask:0xf bound_ctrl:0")

__device__ __forceinline__ float rl63(float x) {
    return __int_as_float(__builtin_amdgcn_readlane(__float_as_int(x), 63));
}

__device__ __forceinline__ float fast_tanh(float x) {
    float e = __builtin_amdgcn_exp2f(-2.8853900817779268f * __builtin_fabsf(x));
    float t = (1.0f - e) * __builtin_amdgcn_rcpf(1.0f + e);
    return __builtin_copysignf(t, x);
}

// ---------------------------------------------------------------------------
// CSR build. ei is [2,E] flat int32. Per-node incidence list partitioned as
// [edges < E/2 | edges >= E/2]. Payload: mode=1 -> edge_id | role<<31,
// mode=0 -> other-endpoint | role<<31 (fallback).
// ---------------------------------------------------------------------------
__global__ __launch_bounds__(256) void csr_count2(const int* __restrict__ ei,
                                                  int* __restrict__ cnt,
                                                  int* __restrict__ cntA) {
    int i = blockIdx.x * 256 + threadIdx.x;
    if (i >= 2 * EE) return;
    int node = ei[i];
    atomicAdd(&cnt[node], 1);
    int e = (i < EE) ? i : i - EE;
    if (e < EH) atomicAdd(&cntA[node], 1);
}

__global__ __launch_bounds__(256) void scanA(const int* __restrict__ cnt,
                                             int* __restrict__ offs,
                                             int* __restrict__ bsum) {
    __shared__ int tmp[256];
    int i = blockIdx.x * 256 + threadIdx.x;
    int v = (i < NN) ? cnt[i] : 0;
    tmp[threadIdx.x] = v;
    __syncthreads();
    int acc = v;
    for (int d = 1; d < 256; d <<= 1) {
        int t = (threadIdx.x >= d) ? tmp[threadIdx.x - d] : 0;
        __syncthreads();
        acc += t;
        tmp[threadIdx.x] = acc;
        __syncthreads();
    }
    if (i < NN) offs[i] = acc - v;
    if (threadIdx.x == 255) bsum[blockIdx.x] = acc;
}

__global__ __launch_bounds__(256) void scanB(int* __restrict__ bsum) {
    __shared__ int tmp[256];
    int v = (threadIdx.x < NB_SCAN) ? bsum[threadIdx.x] : 0;
    tmp[threadIdx.x] = v;
    __syncthreads();
    int acc = v;
    for (int d = 1; d < 256; d <<= 1) {
        int t = (threadIdx.x >= d) ? tmp[threadIdx.x - d] : 0;
        __syncthreads();
        acc += t;
        tmp[threadIdx.x] = acc;
        __syncthreads();
    }
    if (threadIdx.x < NB_SCAN) bsum[threadIdx.x] = acc - v;
}

__global__ __launch_bounds__(256) void scanC2(int* __restrict__ offs,
                                              const int* __restrict__ cntA,
                                              int* __restrict__ curA,
                                              int* __restrict__ curB,
                                              const int* __restrict__ bsum) {
    int i = blockIdx.x * 256 + threadIdx.x;
    if (i < NN) {
        int o = offs[i] + bsum[blockIdx.x];
        offs[i] = o;
        curA[i] = o;
        curB[i] = o + cntA[i];
    }
}

__global__ __launch_bounds__(256) void csr_fill2(const int* __restrict__ ei,
                                                 int* __restrict__ curA,
                                                 int* __restrict__ curB,
                                                 int* __restrict__ adj,
                                                 int mode) {
    int i = blockIdx.x * 256 + threadIdx.x;
    if (i >= 2 * EE) return;
    int node = ei[i];
    int role = (i >= EE) ? 1 : 0;
    int e    = role ? i - EE : i;
    int payload = mode ? e : (role ? ei[i - EE] : ei[i + EE]);
    int p = (e < EH) ? atomicAdd(&curA[node], 1) : atomicAdd(&curB[node], 1);
    adj[p] = payload | (role << 31);
}

// ---------------------------------------------------------------------------
// G = W @ W^T  (64x64). One block.
// ---------------------------------------------------------------------------
__global__ __launch_bounds__(256) void make_G(const float* __restrict__ W,
                                              float* __restrict__ G) {
    __shared__ float Ws[64 * 64];
    for (int t = threadIdx.x; t < 64 * 64; t += 256) Ws[t] = W[t];
    __syncthreads();
    for (int t = threadIdx.x; t < 64 * 64; t += 256) {
        int i = t >> 6, j = t & 63;
        float acc = 0.f;
#pragma unroll 8
        for (int k = 0; k < 64; ++k) acc += Ws[i * 64 + k] * Ws[j * 64 + k];
        G[t] = acc;
    }
}

// ---------------------------------------------------------------------------
// extractor: xh = x@We^T + be ; h0 = xh@U^T + bU ; xU = h0 / nf
// ---------------------------------------------------------------------------
__global__ __launch_bounds__(256) void extractor(
        const float* __restrict__ x, const float* __restrict__ nf,
        const float* __restrict__ We, const float* __restrict__ be,
        const float* __restrict__ U,  const float* __restrict__ bU,
        float* __restrict__ xh, float* __restrict__ xU, float* __restrict__ h0) {
    __shared__ float WeT[INC * HH];
    __shared__ float UT[HH * HH];
    __shared__ float beS[HH], bUS[HH];
    __shared__ float xs[4][INC];
    __shared__ float xhs[4][HH];

    for (int t = threadIdx.x; t < INC * HH; t += 256) {
        int j = t >> 7, k = t & 127;
        WeT[k * 64 + j] = We[t];
    }
    for (int t = threadIdx.x; t < HH * HH; t += 256) {
        int j = t >> 6, k = t & 63;
        UT[k * 64 + j] = U[t];
    }
    if (threadIdx.x < 64) { beS[threadIdx.x] = be[threadIdx.x]; bUS[threadIdx.x] = bU[threadIdx.x]; }
    __syncthreads();

    int lane = threadIdx.x & 63;
    int wv   = threadIdx.x >> 6;

    for (int n0 = blockIdx.x * 4; n0 < NN; n0 += gridDim.x * 4) {
        int n = n0 + wv;
        bool valid = n < NN;
        if (valid) {
            xs[wv][lane]      = x[(size_t)n * INC + lane];
            xs[wv][lane + 64] = x[(size_t)n * INC + lane + 64];
        }
        __syncthreads();
        float acc = beS[lane];
        if (valid) {
#pragma unroll 8
            for (int k = 0; k < INC; ++k) acc += xs[wv][k] * WeT[k * 64 + lane];
            xh[n * 64 + lane] = acc;
            xhs[wv][lane] = acc;
        }
        __syncthreads();
        if (valid) {
            float acc2 = bUS[lane];
#pragma unroll 8
            for (int k = 0; k < HH; ++k) acc2 += xhs[wv][k] * UT[k * 64 + lane];
            h0[n * 64 + lane] = acc2;
            xU[n * 64 + lane] = acc2 / nf[n];
        }
        __syncthreads();
    }
}

// ---------------------------------------------------------------------------
// FAST K1: edges [lo, lo+EH): once per edge, d = tanh(h_r - h_c), DPP stats,
// store NORMALIZED message rho = rsig*(d-mu) as int16 (scale 4096).
// |rho| <= 63/8 = 7.875 -> |q| <= 32256, fits int16 exactly.
// 64-edge chunks (EH % 64 == 0), quad loop, one-quad-ahead prefetch.
// ---------------------------------------------------------------------------
__global__ __launch_bounds__(256) void edge_msg16(
        const int* __restrict__ ei, const float* __restrict__ hcur,
        short* __restrict__ d16, int lo) {
    const int lane = threadIdx.x & 63, wv = threadIdx.x >> 6;
    const int wid = blockIdx.x * 4 + wv;
    const int nw  = gridDim.x * 4;

    for (int chunk = wid; chunk < EH / 64; chunk += nw) {
        const int e0 = lo + chunk * 64;
        const int rv = ei[e0 + lane];
        const int cv = ei[EE + e0 + lane];
        const size_t sbase = (size_t)(chunk * 64) * 64 + lane;

        float hr0, hr1, hr2, hr3, hc0, hc1, hc2, hc3;
        {
            int r0 = __builtin_amdgcn_readlane(rv, 0);
            int r1 = __builtin_amdgcn_readlane(rv, 1);
            int r2 = __builtin_amdgcn_readlane(rv, 2);
            int r3 = __builtin_amdgcn_readlane(rv, 3);
            int c0 = __builtin_amdgcn_readlane(cv, 0);
            int c1 = __builtin_amdgcn_readlane(cv, 1);
            int c2 = __builtin_amdgcn_readlane(cv, 2);
            int c3 = __builtin_amdgcn_readlane(cv, 3);
            hr0 = hcur[(size_t)r0 * 64 + lane];
            hr1 = hcur[(size_t)r1 * 64 + lane];
            hr2 = hcur[(size_t)r2 * 64 + lane];
            hr3 = hcur[(size_t)r3 * 64 + lane];
            hc0 = hcur[(size_t)c0 * 64 + lane];
            hc1 = hcur[(size_t)c1 * 64 + lane];
            hc2 = hcur[(size_t)c2 * 64 + lane];
            hc3 = hcur[(size_t)c3 * 64 + lane];
        }

        for (int q = 0; q < 16; ++q) {
            const int j0 = q << 2;
            float nr0, nr1, nr2, nr3, nc0, nc1, nc2, nc3;
            {
                int ja = (j0 + 4) & 63, jb = (j0 + 5) & 63;
                int jc = (j0 + 6) & 63, jd = (j0 + 7) & 63;
                int r0 = __builtin_amdgcn_readlane(rv, ja);
                int r1 = __builtin_amdgcn_readlane(rv, jb);
                int r2 = __builtin_amdgcn_readlane(rv, jc);
                int r3 = __builtin_amdgcn_readlane(rv, jd);
                int c0 = __builtin_amdgcn_readlane(cv, ja);
                int c1 = __builtin_amdgcn_readlane(cv, jb);
                int c2 = __builtin_amdgcn_readlane(cv, jc);
                int c3 = __builtin_amdgcn_readlane(cv, jd);
                nr0 = hcur[(size_t)r0 * 64 + lane];
                nr1 = hcur[(size_t)r1 * 64 + lane];
                nr2 = hcur[(size_t)r2 * 64 + lane];
                nr3 = hcur[(size_t)r3 * 64 + lane];
                nc0 = hcur[(size_t)c0 * 64 + lane];
                nc1 = hcur[(size_t)c1 * 64 + lane];
                nc2 = hcur[(size_t)c2 * 64 + lane];
                nc3 = hcur[(size_t)c3 * 64 + lane];
            }

            float d0 = fast_tanh(hr0 - hc0);
            float d1 = fast_tanh(hr1 - hc1);
            float d2 = fast_tanh(hr2 - hc2);
            float d3 = fast_tanh(hr3 - hc3);
            float s0 = d0, s1 = d1, s2 = d2, s3 = d3;
            float s4 = d0 * d0, s5 = d1 * d1, s6 = d2 * d2, s7 = d3 * d3;
            DPP_ALL6();
            float t10 = rl63(s0), t11 = rl63(s1), t12 = rl63(s2), t13 = rl63(s3);
            float t20 = rl63(s4), t21 = rl63(s5), t22 = rl63(s6), t23 = rl63(s7);

            float mu0 = t10 * 0.015625f, mu1 = t11 * 0.015625f;
            float mu2 = t12 * 0.015625f, mu3 = t13 * 0.015625f;
            float v0 = __builtin_fmaf(t20, 0.015625f, -mu0 * mu0);
            float v1 = __builtin_fmaf(t21, 0.015625f, -mu1 * mu1);
            float v2 = __builtin_fmaf(t22, 0.015625f, -mu2 * mu2);
            float v3 = __builtin_fmaf(t23, 0.015625f, -mu3 * mu3);
            v0 = v0 > 0.f ? v0 : 0.f;  v1 = v1 > 0.f ? v1 : 0.f;
            v2 = v2 > 0.f ? v2 : 0.f;  v3 = v3 > 0.f ? v3 : 0.f;
            float rs0 = __frsqrt_rn(v0 + LN_EPS) * QSCALE;
            float rs1 = __frsqrt_rn(v1 + LN_EPS) * QSCALE;
            float rs2 = __frsqrt_rn(v2 + LN_EPS) * QSCALE;
            float rs3 = __frsqrt_rn(v3 + LN_EPS) * QSCALE;

            int q0 = __float2int_rn((d0 - mu0) * rs0);
            int q1 = __float2int_rn((d1 - mu1) * rs1);
            int q2 = __float2int_rn((d2 - mu2) * rs2);
            int q3 = __float2int_rn((d3 - mu3) * rs3);
            d16[sbase + (size_t)(j0 + 0) * 64] = (short)q0;
            d16[sbase + (size_t)(j0 + 1) * 64] = (short)q1;
            d16[sbase + (size_t)(j0 + 2) * 64] = (short)q2;
            d16[sbase + (size_t)(j0 + 3) * 64] = (short)q3;

            hr0 = nr0; hr1 = nr1; hr2 = nr2; hr3 = nr3;
            hc0 = nc0; hc1 = nc1; hc2 = nc2; hc3 = nc3;
        }
    }
}

// ---------------------------------------------------------------------------
// FAST K2: per node, integer-accumulate +/- q over one incidence segment.
// phase 0 (A-half): Tq,sigma -> scratch (dead hnxt buffer) + sig[].
// phase 1 (B-half): resume from scratch, then epilogue:
//   av = nf*(g*Tq/4096 + b*sigma) ; p = av@G ; y,s,h updates.
// ---------------------------------------------------------------------------
__global__ __launch_bounds__(256) void gather_half(
        const int* __restrict__ adj, const int* __restrict__ offs,
        const int* __restrict__ cntA, const int* __restrict__ cnt,
        const short* __restrict__ d16, int lo, int phase,
        const float* __restrict__ nf, const float* __restrict__ gamma,
        const float* __restrict__ beta, const float* __restrict__ Gm,
        const float* __restrict__ xU,
        float* __restrict__ y, float* __restrict__ s,
        float* __restrict__ scratch, int* __restrict__ sig,
        float* __restrict__ hnxt, int last) {
    __shared__ float Gs[64 * 64];
    for (int t = threadIdx.x; t < 64 * 64; t += 256) Gs[t] = Gm[t];
    __syncthreads();

    const int lane = threadIdx.x & 63, wv = threadIdx.x >> 6;
    const float g = gamma[lane], b = beta[lane];
    int* scri = (int*)scratch;

    for (int n = blockIdx.x * 4 + wv; n < NN; n += gridDim.x * 4) {
        const int base0 = offs[n], ca = cntA[n], dg = cnt[n];
        const int start = phase ? base0 + ca : base0;
        const int len   = phase ? dg - ca : ca;
        int Tq = 0, sigma = 0;
        if (phase) { Tq = scri[n * 64 + lane]; sigma = sig[n]; }

        for (int c = 0; c < len; c += 64) {
            int nv = len - c; nv = nv < 64 ? nv : 64;
            int li = lane < nv ? lane : nv - 1;
            int ev = adj[start + c + li];
            unsigned long long bal = __ballot(ev < 0);
            unsigned long long msk = (nv >= 64) ? ~0ull : ((1ull << nv) - 1ull);
            sigma += nv - 2 * __builtin_popcountll(bal & msk);

            // prefetch quad 0
            int b0, b1, b2, b3, e0s, e1s, e2s, e3s;
            {
                int jb = 1 < nv ? 1 : nv - 1;
                int jc = 2 < nv ? 2 : nv - 1;
                int jd = 3 < nv ? 3 : nv - 1;
                e0s = __builtin_amdgcn_readlane(ev, 0);
                e1s = __builtin_amdgcn_readlane(ev, jb);
                e2s = __builtin_amdgcn_readlane(ev, jc);
                e3s = __builtin_amdgcn_readlane(ev, jd);
                b0 = d16[(size_t)(((unsigned)e0s & 0x7fffffffu) - lo) * 64 + lane];
                b1 = d16[(size_t)(((unsigned)e1s & 0x7fffffffu) - lo) * 64 + lane];
                b2 = d16[(size_t)(((unsigned)e2s & 0x7fffffffu) - lo) * 64 + lane];
                b3 = d16[(size_t)(((unsigned)e3s & 0x7fffffffu) - lo) * 64 + lane];
            }

            const int quads = (nv + 3) >> 2;
            for (int qq = 0; qq < quads; ++qq) {
                const int j0 = qq << 2;
                int nb0, nb1, nb2, nb3, ne0, ne1, ne2, ne3;
                {
                    int ja = j0 + 4; ja = ja < nv ? ja : nv - 1;
                    int jb = j0 + 5; jb = jb < nv ? jb : nv - 1;
                    int jc = j0 + 6; jc = jc < nv ? jc : nv - 1;
                    int jd = j0 + 7; jd = jd < nv ? jd : nv - 1;
                    ne0 = __builtin_amdgcn_readlane(ev, ja);
                    ne1 = __builtin_amdgcn_readlane(ev, jb);
                    ne2 = __builtin_amdgcn_readlane(ev, jc);
                    ne3 = __builtin_amdgcn_readlane(ev, jd);
                    nb0 = d16[(size_t)(((unsigned)ne0 & 0x7fffffffu) - lo) * 64 + lane];
                    nb1 = d16[(size_t)(((unsigned)ne1 & 0x7fffffffu) - lo) * 64 + lane];
                    nb2 = d16[(size_t)(((unsigned)ne2 & 0x7fffffffu) - lo) * 64 + lane];
                    nb3 = d16[(size_t)(((unsigned)ne3 & 0x7fffffffu) - lo) * 64 + lane];
                }
#pragma unroll
                for (int i = 0; i < 4; ++i) {
                    int ji = j0 + i;
                    int es = (i == 0) ? e0s : (i == 1) ? e1s : (i == 2) ? e2s : e3s;
                    int bv = (i == 0) ? b0  : (i == 1) ? b1  : (i == 2) ? b2  : b3;
                    bv = (ji < nv) ? bv : 0;          // kill tail dupes
                    Tq += (es < 0) ? -bv : bv;        // exact integer accum
                }
                b0 = nb0; b1 = nb1; b2 = nb2; b3 = nb3;
                e0s = ne0; e1s = ne1; e2s = ne2; e3s = ne3;
            }
        }

        if (!phase) {
            scri[n * 64 + lane] = Tq;
            if (lane == 0) sig[n] = sigma;
        } else {
            const float nfn = nf[n];
            const float av  = nfn *
                __builtin_fmaf(g, (float)Tq * QINV, b * (float)sigma);

            float p = 0.f;
            const int avi = __float_as_int(av);
#pragma unroll
            for (int k = 0; k < 64; ++k) {
                float ak = __int_as_float(__builtin_amdgcn_readlane(avi, k));
                p = __builtin_fmaf(ak, Gs[k * 64 + lane], p);
            }

            const float yv = -ALPHA * p + (1.0f - ALPHA) * y[n * 64 + lane];
            y[n * 64 + lane] = yv;
            s[n * 64 + lane] = (1.0f - ALPHA) * s[n * 64 + lane] + av;
            if (!last) hnxt[n * 64 + lane] = nfn * (yv + xU[n * 64 + lane]);
        }
    }
}

// ---------------------------------------------------------------------------
// FALLBACK: R7 fused step (proven 300 us/step). adj holds other|role<<31.
// ---------------------------------------------------------------------------
__global__ __launch_bounds__(256) void fused_step(
        const int* __restrict__ adj, const int* __restrict__ offs,
        const int* __restrict__ cnt,
        const float* __restrict__ hcur, float* __restrict__ hnxt,
        const float* __restrict__ nf, const float* __restrict__ gamma,
        const float* __restrict__ beta, const float* __restrict__ Gm,
        const float* __restrict__ xU,
        float* __restrict__ y, float* __restrict__ s, int last) {
    __shared__ float Gs[64 * 64];
    for (int t = threadIdx.x; t < 64 * 64; t += 256) Gs[t] = Gm[t];
    __syncthreads();

    const int lane = threadIdx.x & 63, wv = threadIdx.x >> 6;
    const float g = gamma[lane], b = beta[lane];

    for (int n = blockIdx.x * 4 + wv; n < NN; n += gridDim.x * 4) {
        const int base = offs[n], deg = cnt[n];
        const float hn = hcur[n * 64 + lane];
        float accM = 0.f;
        int sigma = 0;

        for (int c = 0; c < deg; c += 64) {
            int nv = deg - c; nv = nv < 64 ? nv : 64;
            int li = lane < nv ? lane : nv - 1;
            int ev = adj[base + c + li];
            unsigned long long bal = __ballot(ev < 0);
            unsigned long long msk = (nv >= 64) ? ~0ull : ((1ull << nv) - 1ull);
            sigma += nv - 2 * __builtin_popcountll(bal & msk);

            float hv0, hv1, hv2, hv3;
            {
                int j1c = 1 < nv ? 1 : nv - 1;
                int j2c = 2 < nv ? 2 : nv - 1;
                int j3c = 3 < nv ? 3 : nv - 1;
                int e0 = __builtin_amdgcn_readlane(ev, 0);
                int e1 = __builtin_amdgcn_readlane(ev, j1c);
                int e2 = __builtin_amdgcn_readlane(ev, j2c);
                int e3 = __builtin_amdgcn_readlane(ev, j3c);
                hv0 = hcur[(size_t)((unsigned)e0 & 0x7fffffffu) * 64u + lane];
                hv1 = hcur[(size_t)((unsigned)e1 & 0x7fffffffu) * 64u + lane];
                hv2 = hcur[(size_t)((unsigned)e2 & 0x7fffffffu) * 64u + lane];
                hv3 = hcur[(size_t)((unsigned)e3 & 0x7fffffffu) * 64u + lane];
            }

            const int quads = (nv + 3) >> 2;
            for (int q = 0; q < quads; ++q) {
                const int j0 = q << 2;
                float hn0, hn1, hn2, hn3;
                {
                    int ja = j0 + 4; ja = ja < nv ? ja : nv - 1;
                    int jb = j0 + 5; jb = jb < nv ? jb : nv - 1;
                    int jc = j0 + 6; jc = jc < nv ? jc : nv - 1;
                    int jd = j0 + 7; jd = jd < nv ? jd : nv - 1;
                    int e0 = __builtin_amdgcn_readlane(ev, ja);
                    int e1 = __builtin_amdgcn_readlane(ev, jb);
                    int e2 = __builtin_amdgcn_readlane(ev, jc);
                    int e3 = __builtin_amdgcn_readlane(ev, jd);
                    hn0 = hcur[(size_t)((unsigned)e0 & 0x7fffffffu) * 64u + lane];
                    hn1 = hcur[(size_t)((unsigned)e1 & 0x7fffffffu) * 64u + lane];
                    hn2 = hcur[(size_t)((unsigned)e2 & 0x7fffffffu) * 64u + lane];
                    hn3 = hcur[(size_t)((unsigned)e3 & 0x7fffffffu) * 64u + lane];
                }

                float d0 = fast_tanh(hn - hv0);
                float d1 = fast_tanh(hn - hv1);
                float d2 = fast_tanh(hn - hv2);
                float d3 = fast_tanh(hn - hv3);
                float s0 = d0, s1 = d1, s2 = d2, s3 = d3;
                float s4 = d0 * d0, s5 = d1 * d1, s6 = d2 * d2, s7 = d3 * d3;
                DPP_ALL6();
                float t10 = rl63(s0), t11 = rl63(s1), t12 = rl63(s2), t13 = rl63(s3);
                float t20 = rl63(s4), t21 = rl63(s5), t22 = rl63(s6), t23 = rl63(s7);

                float mu, var, rsig;
                mu = t10 * 0.015625f;
                var = __builtin_fmaf(t20, 0.015625f, -mu * mu);
                var = var > 0.f ? var : 0.f;
                rsig = __frsqrt_rn(var + LN_EPS);
                rsig = (j0 + 0 < nv) ? rsig : 0.f;
                accM = __builtin_fmaf(rsig, d0 - mu, accM);

                mu = t11 * 0.015625f;
                var = __builtin_fmaf(t21, 0.015625f, -mu * mu);
                var = var > 0.f ? var : 0.f;
                rsig = __frsqrt_rn(var + LN_EPS);
                rsig = (j0 + 1 < nv) ? rsig : 0.f;
                accM = __builtin_fmaf(rsig, d1 - mu, accM);

                mu = t12 * 0.015625f;
                var = __builtin_fmaf(t22, 0.015625f, -mu * mu);
                var = var > 0.f ? var : 0.f;
                rsig = __frsqrt_rn(var + LN_EPS);
                rsig = (j0 + 2 < nv) ? rsig : 0.f;
                accM = __builtin_fmaf(rsig, d2 - mu, accM);

                mu = t13 * 0.015625f;
                var = __builtin_fmaf(t23, 0.015625f, -mu * mu);
                var = var > 0.f ? var : 0.f;
                rsig = __frsqrt_rn(var + LN_EPS);
                rsig = (j0 + 3 < nv) ? rsig : 0.f;
                accM = __builtin_fmaf(rsig, d3 - mu, accM);

                hv0 = hn0; hv1 = hn1; hv2 = hn2; hv3 = hn3;
            }
        }

        const float nfn = nf[n];
        const float av  = nfn * __builtin_fmaf(g, accM, b * (float)sigma);

        float p = 0.f;
        const int avi = __float_as_int(av);
#pragma unroll
        for (int k = 0; k < 64; ++k) {
            float ak = __int_as_float(__builtin_amdgcn_readlane(avi, k));
            p = __builtin_fmaf(ak, Gs[k * 64 + lane], p);
        }

        const float yv = -ALPHA * p + (1.0f - ALPHA) * y[n * 64 + lane];
        y[n * 64 + lane] = yv;
        s[n * 64 + lane] = (1.0f - ALPHA) * s[n * 64 + lane] + av;
        if (!last) hnxt[n * 64 + lane] = nfn * (yv + xU[n * 64 + lane]);
    }
}

// ---------------------------------------------------------------------------
// final: z = -alpha*(s@W) ; zf = nf*z + xh ; out = zf@Wlast^T + blast
// ---------------------------------------------------------------------------
__global__ __launch_bounds__(256) void final_out(
        const float* __restrict__ s, const float* __restrict__ xh,
        const float* __restrict__ nf, const float* __restrict__ W,
        const float* __restrict__ Wlast, const float* __restrict__ blast,
        float* __restrict__ out) {
    __shared__ float Ws[64 * 64];
    __shared__ float WlT[64 * OUTC];
    __shared__ float blS[OUTC];
    __shared__ float ss[4][64];
    __shared__ float zfs[4][64];
    for (int t = threadIdx.x; t < 64 * 64; t += 256) Ws[t] = W[t];
    for (int t = threadIdx.x; t < OUTC * 64; t += 256) {
        int o = t >> 6, j = t & 63;
        WlT[j * OUTC + o] = Wlast[t];
    }
    if (threadIdx.x < OUTC) blS[threadIdx.x] = blast[threadIdx.x];
    __syncthreads();
    int lane = threadIdx.x & 63, wv = threadIdx.x >> 6;
    for (int n0 = blockIdx.x * 4; n0 < NN; n0 += gridDim.x * 4) {
        int n = n0 + wv;
        if (n < NN) ss[wv][lane] = s[n * 64 + lane];
        __syncthreads();
        if (n < NN) {
            float z = 0.f;
#pragma unroll 8
            for (int k = 0; k < 64; ++k) z += ss[wv][k] * Ws[k * 64 + lane];
            z *= -ALPHA;
            zfs[wv][lane] = nf[n] * z + xh[n * 64 + lane];
        }
        __syncthreads();
        if (n < NN && lane < OUTC) {
            float acc = blS[lane];
#pragma unroll 8
            for (int j = 0; j < 64; ++j) acc += zfs[wv][j] * WlT[j * OUTC + lane];
            out[n * OUTC + lane] = acc;
        }
        __syncthreads();
    }
}

// ---------------------------------------------------------------------------
extern "C" void kernel_launch(void* const* d_in, const int* in_sizes, int n_in,
                              void* d_out, int out_size, void* d_ws, size_t ws_size,
                              hipStream_t stream) {
    const float* x     = (const float*)d_in[0];
    const int*   ei    = (const int*)  d_in[1];
    const float* nf    = (const float*)d_in[2];
    const float* We    = (const float*)d_in[3];
    const float* be    = (const float*)d_in[4];
    const float* W     = (const float*)d_in[5];
    const float* U     = (const float*)d_in[6];
    const float* bU    = (const float*)d_in[7];
    const float* gamma = (const float*)d_in[8];
    const float* beta  = (const float*)d_in[9];
    const float* Wlast = (const float*)d_in[10];
    const float* blast = (const float*)d_in[11];
    float* out = (float*)d_out;

    char* ws = (char*)d_ws;
    size_t off = 0;
    const size_t NH = (size_t)NN * HH * sizeof(float);
    int*   adj  = (int*)(ws + off);   off += (size_t)2 * EE * sizeof(int);
    int*   offs = (int*)(ws + off);   off += (size_t)NN * sizeof(int);
    int*   cnt  = (int*)(ws + off);   off += (size_t)NN * sizeof(int);
    int*   cntA = (int*)(ws + off);   off += (size_t)NN * sizeof(int);
    int*   curA = (int*)(ws + off);   off += (size_t)NN * sizeof(int);
    int*   curB = (int*)(ws + off);   off += (size_t)NN * sizeof(int);
    int*   sig  = (int*)(ws + off);   off += (size_t)NN * sizeof(int);
    int*   bsum = (int*)(ws + off);   off += 256 * sizeof(int);
    float* xh   = (float*)(ws + off); off += NH;
    float* xU   = (float*)(ws + off); off += NH;
    float* h0   = (float*)(ws + off); off += NH;
    float* h1   = (float*)(ws + off); off += NH;
    float* y    = (float*)(ws + off); off += NH;
    float* s    = (float*)(ws + off); off += NH;
    float* G    = (float*)(ws + off); off += (size_t)HH * HH * sizeof(float);
    short* d16  = (short*)(ws + off);
    size_t need_fast = off + (size_t)EH * HH * sizeof(short);   // ~193.6 MB
    const int fast = (ws_size >= need_fast) ? 1 : 0;

    hipMemsetAsync(cnt, 0, (size_t)2 * NN * sizeof(int), stream);  // cnt+cntA
    hipMemsetAsync(y, 0, 2 * NH, stream);   // y and s are adjacent

    // CSR build (once per launch), per-node partitioned [A-half | B-half]
    csr_count2<<<(2 * EE + 255) / 256, 256, 0, stream>>>(ei, cnt, cntA);
    scanA<<<NB_SCAN, 256, 0, stream>>>(cnt, offs, bsum);
    scanB<<<1, 256, 0, stream>>>(bsum);
    scanC2<<<NB_SCAN, 256, 0, stream>>>(offs, cntA, curA, curB, bsum);
    csr_fill2<<<(2 * EE + 255) / 256, 256, 0, stream>>>(ei, curA, curB, adj, fast);

    make_G<<<1, 256, 0, stream>>>(W, G);
    extractor<<<2048, 256, 0, stream>>>(x, nf, We, be, U, bU, xh, xU, h0);

    float* hc = h0;
    float* hn = h1;
    if (fast) {
        for (int t = 0; t < 4; ++t) {
            int last = (t == 3);
            edge_msg16<<<3125, 256, 0, stream>>>(ei, hc, d16, 0);
            gather_half<<<2048, 256, 0, stream>>>(adj, offs, cntA, cnt, d16, 0, 0,
                                                  nf, gamma, beta, G, xU, y, s,
                                                  hn, sig, hn, last);
            edge_msg16<<<3125, 256, 0, stream>>>(ei, hc, d16, EH);
            gather_half<<<2048, 256, 0, stream>>>(adj, offs, cntA, cnt, d16, EH, 1,
                                                  nf, gamma, beta, G, xU, y, s,
                                                  hn, sig, hn, last);
            float* tmp = hc; hc = hn; hn = tmp;
        }
    } else {
        for (int t = 0; t < 4; ++t) {
            fused_step<<<2048, 256, 0, stream>>>(adj, offs, cnt, hc, hn, nf,
                                                 gamma, beta, G, xU, y, s, t == 3);
            float* tmp = hc; hc = hn; hn = tmp;
        }
    }
    final_out<<<2048, 256, 0, stream>>>(s, xh, nf, W, Wlast, blast, out);
}

// Round 10
// 1530.222 us; speedup vs baseline: 1.6791x; 1.1680x over previous
//
#include <hip/hip_runtime.h>
#include <hip/hip_bf16.h>

// Problem constants (from reference)
#define NN   50000
#define EE   1600000
#define INC  128
#define HH   64
#define OUTC 40
#define ALPHA 0.8f
#define LN_EPS 1e-5f
#define NB_SCAN 196   // ceil(NN/256)

// ---------------------------------------------------------------------------
// Wave64 sum via fused v_add_f32_dpp (inline asm; 1 inst/stage guaranteed).
// 8 independent chains interleaved (also satisfies DPP wait-states).
// Total lands in lane 63.
// ---------------------------------------------------------------------------
#define DPP8(CTRL)                                                             \
    asm volatile(                                                              \
        "v_add_f32_dpp %0, %0, %0 " CTRL "\n\t"                                \
        "v_add_f32_dpp %1, %1, %1 " CTRL "\n\t"                                \
        "v_add_f32_dpp %2, %2, %2 " CTRL "\n\t"                                \
        "v_add_f32_dpp %3, %3, %3 " CTRL "\n\t"                                \
        "v_add_f32_dpp %4, %4, %4 " CTRL "\n\t"                                \
        "v_add_f32_dpp %5, %5, %5 " CTRL "\n\t"                                \
        "v_add_f32_dpp %6, %6, %6 " CTRL "\n\t"                                \
        "v_add_f32_dpp %7, %7, %7 " CTRL                                       \
        : "+v"(s0), "+v"(s1), "+v"(s2), "+v"(s3),                              \
          "+v"(s4), "+v"(s5), "+v"(s6), "+v"(s7))

#define DPP_ALL6()                                                             \
    DPP8("row_shr:1 row_mask:0xf bank_mask:0xf bound_ctrl:0");                 \
    DPP8("row_shr:2 row_mask:0xf bank_mask:0xf bound_ctrl:0");                 \
    DPP8("row_shr:4 row_mask:0xf bank_mask:0xf bound_ctrl:0");                 \
    DPP8("row_shr:8 row_mask:0xf bank_mask:0xf bound_ctrl:0");                 \
    DPP8("row_bcast:15 row_mask:0xa bank_mask:0xf bound_ctrl:0");              \
    DPP8("row_bcast:31 row_mask:0xc bank_mask:0xf bound_ctrl:0")

__device__ __forceinline__ float rl63(float x) {
    return __int_as_float(__builtin_amdgcn_readlane(__float_as_int(x), 63));
}

__device__ __forceinline__ float fast_tanh(float x) {
    float e = __builtin_amdgcn_exp2f(-2.8853900817779268f * __builtin_fabsf(x));
    float t = (1.0f - e) * __builtin_amdgcn_rcpf(1.0f + e);
    return __builtin_copysignf(t, x);
}

// ---------------------------------------------------------------------------
// CSR build, atomic-light. ei is [2,E] flat int32.
// Pass 1 (count): one atomicAdd per incidence; the RETURNED old value is the
//   incidence's rank within its node -> stored to rank16[] (streaming 6.4 MB).
// Pass 2 (fill): NO atomics — adj[offs[node] + rank16[i]] = other|role<<31.
//   Scattered 4B stores into 12.8 MB (L2-cached, written back once) instead
//   of 3.2M memory-side RMWs (192 MB HBM traffic measured in R9).
// ---------------------------------------------------------------------------
__global__ __launch_bounds__(256) void csr_count(const int* __restrict__ ei,
                                                 int* __restrict__ cnt,
                                                 unsigned short* __restrict__ rank16) {
    int i = blockIdx.x * 256 + threadIdx.x;
    if (i >= 2 * EE) return;
    int r = atomicAdd(&cnt[ei[i]], 1);
    rank16[i] = (unsigned short)r;
}

__global__ __launch_bounds__(256) void scanA(const int* __restrict__ cnt,
                                             int* __restrict__ offs,
                                             int* __restrict__ bsum) {
    __shared__ int tmp[256];
    int i = blockIdx.x * 256 + threadIdx.x;
    int v = (i < NN) ? cnt[i] : 0;
    tmp[threadIdx.x] = v;
    __syncthreads();
    int acc = v;
    for (int d = 1; d < 256; d <<= 1) {
        int t = (threadIdx.x >= d) ? tmp[threadIdx.x - d] : 0;
        __syncthreads();
        acc += t;
        tmp[threadIdx.x] = acc;
        __syncthreads();
    }
    if (i < NN) offs[i] = acc - v;
    if (threadIdx.x == 255) bsum[blockIdx.x] = acc;
}

__global__ __launch_bounds__(256) void scanB(int* __restrict__ bsum) {
    __shared__ int tmp[256];
    int v = (threadIdx.x < NB_SCAN) ? bsum[threadIdx.x] : 0;
    tmp[threadIdx.x] = v;
    __syncthreads();
    int acc = v;
    for (int d = 1; d < 256; d <<= 1) {
        int t = (threadIdx.x >= d) ? tmp[threadIdx.x - d] : 0;
        __syncthreads();
        acc += t;
        tmp[threadIdx.x] = acc;
        __syncthreads();
    }
    if (threadIdx.x < NB_SCAN) bsum[threadIdx.x] = acc - v;
}

__global__ __launch_bounds__(256) void scanC(int* __restrict__ offs,
                                             const int* __restrict__ bsum) {
    int i = blockIdx.x * 256 + threadIdx.x;
    if (i < NN) offs[i] += bsum[blockIdx.x];
}

__global__ __launch_bounds__(256) void csr_fill(const int* __restrict__ ei,
                                                const int* __restrict__ offs,
                                                const unsigned short* __restrict__ rank16,
                                                int* __restrict__ adj) {
    int i = blockIdx.x * 256 + threadIdx.x;
    if (i >= 2 * EE) return;
    int node  = ei[i];
    int role  = (i >= EE) ? 1 : 0;
    int other = role ? ei[i - EE] : ei[i + EE];
    adj[offs[node] + (int)rank16[i]] = other | (role << 31);
}

// ---------------------------------------------------------------------------
// G = W @ W^T  (64x64). One block.
// ---------------------------------------------------------------------------
__global__ __launch_bounds__(256) void make_G(const float* __restrict__ W,
                                              float* __restrict__ G) {
    __shared__ float Ws[64 * 64];
    for (int t = threadIdx.x; t < 64 * 64; t += 256) Ws[t] = W[t];
    __syncthreads();
    for (int t = threadIdx.x; t < 64 * 64; t += 256) {
        int i = t >> 6, j = t & 63;
        float acc = 0.f;
#pragma unroll 8
        for (int k = 0; k < 64; ++k) acc += Ws[i * 64 + k] * Ws[j * 64 + k];
        G[t] = acc;
    }
}

// ---------------------------------------------------------------------------
// extractor: xh = x@We^T + be ; h0 = xh@U^T + bU ; xU = h0 / nf
// ---------------------------------------------------------------------------
__global__ __launch_bounds__(256) void extractor(
        const float* __restrict__ x, const float* __restrict__ nf,
        const float* __restrict__ We, const float* __restrict__ be,
        const float* __restrict__ U,  const float* __restrict__ bU,
        float* __restrict__ xh, float* __restrict__ xU, float* __restrict__ h0) {
    __shared__ float WeT[INC * HH];
    __shared__ float UT[HH * HH];
    __shared__ float beS[HH], bUS[HH];
    __shared__ float xs[4][INC];
    __shared__ float xhs[4][HH];

    for (int t = threadIdx.x; t < INC * HH; t += 256) {
        int j = t >> 7, k = t & 127;
        WeT[k * 64 + j] = We[t];
    }
    for (int t = threadIdx.x; t < HH * HH; t += 256) {
        int j = t >> 6, k = t & 63;
        UT[k * 64 + j] = U[t];
    }
    if (threadIdx.x < 64) { beS[threadIdx.x] = be[threadIdx.x]; bUS[threadIdx.x] = bU[threadIdx.x]; }
    __syncthreads();

    int lane = threadIdx.x & 63;
    int wv   = threadIdx.x >> 6;

    for (int n0 = blockIdx.x * 4; n0 < NN; n0 += gridDim.x * 4) {
        int n = n0 + wv;
        bool valid = n < NN;
        if (valid) {
            xs[wv][lane]      = x[(size_t)n * INC + lane];
            xs[wv][lane + 64] = x[(size_t)n * INC + lane + 64];
        }
        __syncthreads();
        float acc = beS[lane];
        if (valid) {
#pragma unroll 8
            for (int k = 0; k < INC; ++k) acc += xs[wv][k] * WeT[k * 64 + lane];
            xh[n * 64 + lane] = acc;
            xhs[wv][lane] = acc;
        }
        __syncthreads();
        if (valid) {
            float acc2 = bUS[lane];
#pragma unroll 8
            for (int k = 0; k < HH; ++k) acc2 += xhs[wv][k] * UT[k * 64 + lane];
            h0[n * 64 + lane] = acc2;
            xU[n * 64 + lane] = acc2 / nf[n];
        }
        __syncthreads();
    }
}

// ---------------------------------------------------------------------------
// fused step (R7, proven 300 us/step): per node n (one wave, lane = channel).
// Quad inner loop, one-quad-ahead clamped prefetch, 8 lock-step fused
// v_add_f32_dpp reduction chains. Per node:
//   accM  = sum_e rsig_e*(d_e - mu_e)     (gamma hoisted)
//   sigma = deg - 2*ncol                  (beta hoisted; exact via ballot)
//   a = nf*(g*accM + b*sigma) ; p = a@G ; y,s,h updates. No atomics.
// ---------------------------------------------------------------------------
__global__ __launch_bounds__(256) void fused_step(
        const int* __restrict__ adj, const int* __restrict__ offs,
        const int* __restrict__ cnt,
        const float* __restrict__ hcur, float* __restrict__ hnxt,
        const float* __restrict__ nf, const float* __restrict__ gamma,
        const float* __restrict__ beta, const float* __restrict__ Gm,
        const float* __restrict__ xU,
        float* __restrict__ y, float* __restrict__ s, int last) {
    __shared__ float Gs[64 * 64];
    for (int t = threadIdx.x; t < 64 * 64; t += 256) Gs[t] = Gm[t];
    __syncthreads();

    const int lane = threadIdx.x & 63, wv = threadIdx.x >> 6;
    const float g = gamma[lane], b = beta[lane];

    for (int n = blockIdx.x * 4 + wv; n < NN; n += gridDim.x * 4) {
        const int base = offs[n], deg = cnt[n];
        const float hn = hcur[n * 64 + lane];
        float accM = 0.f;
        int sigma = 0;

        for (int c = 0; c < deg; c += 64) {
            int nv = deg - c; nv = nv < 64 ? nv : 64;
            int li = lane < nv ? lane : nv - 1;
            int ev = adj[base + c + li];
            unsigned long long bal = __ballot(ev < 0);
            unsigned long long msk = (nv >= 64) ? ~0ull : ((1ull << nv) - 1ull);
            sigma += nv - 2 * __builtin_popcountll(bal & msk);

            float hv0, hv1, hv2, hv3;
            {
                int j1c = 1 < nv ? 1 : nv - 1;
                int j2c = 2 < nv ? 2 : nv - 1;
                int j3c = 3 < nv ? 3 : nv - 1;
                int e0 = __builtin_amdgcn_readlane(ev, 0);
                int e1 = __builtin_amdgcn_readlane(ev, j1c);
                int e2 = __builtin_amdgcn_readlane(ev, j2c);
                int e3 = __builtin_amdgcn_readlane(ev, j3c);
                hv0 = hcur[(size_t)((unsigned)e0 & 0x7fffffffu) * 64u + lane];
                hv1 = hcur[(size_t)((unsigned)e1 & 0x7fffffffu) * 64u + lane];
                hv2 = hcur[(size_t)((unsigned)e2 & 0x7fffffffu) * 64u + lane];
                hv3 = hcur[(size_t)((unsigned)e3 & 0x7fffffffu) * 64u + lane];
            }

            const int quads = (nv + 3) >> 2;
            for (int q = 0; q < quads; ++q) {
                const int j0 = q << 2;
                float hn0, hn1, hn2, hn3;
                {
                    int ja = j0 + 4; ja = ja < nv ? ja : nv - 1;
                    int jb = j0 + 5; jb = jb < nv ? jb : nv - 1;
                    int jc = j0 + 6; jc = jc < nv ? jc : nv - 1;
                    int jd = j0 + 7; jd = jd < nv ? jd : nv - 1;
                    int e0 = __builtin_amdgcn_readlane(ev, ja);
                    int e1 = __builtin_amdgcn_readlane(ev, jb);
                    int e2 = __builtin_amdgcn_readlane(ev, jc);
                    int e3 = __builtin_amdgcn_readlane(ev, jd);
                    hn0 = hcur[(size_t)((unsigned)e0 & 0x7fffffffu) * 64u + lane];
                    hn1 = hcur[(size_t)((unsigned)e1 & 0x7fffffffu) * 64u + lane];
                    hn2 = hcur[(size_t)((unsigned)e2 & 0x7fffffffu) * 64u + lane];
                    hn3 = hcur[(size_t)((unsigned)e3 & 0x7fffffffu) * 64u + lane];
                }

                float d0 = fast_tanh(hn - hv0);
                float d1 = fast_tanh(hn - hv1);
                float d2 = fast_tanh(hn - hv2);
                float d3 = fast_tanh(hn - hv3);
                float s0 = d0, s1 = d1, s2 = d2, s3 = d3;
                float s4 = d0 * d0, s5 = d1 * d1, s6 = d2 * d2, s7 = d3 * d3;
                DPP_ALL6();
                float t10 = rl63(s0), t11 = rl63(s1), t12 = rl63(s2), t13 = rl63(s3);
                float t20 = rl63(s4), t21 = rl63(s5), t22 = rl63(s6), t23 = rl63(s7);

                float mu, var, rsig;
                mu = t10 * 0.015625f;
                var = __builtin_fmaf(t20, 0.015625f, -mu * mu);
                var = var > 0.f ? var : 0.f;
                rsig = __frsqrt_rn(var + LN_EPS);
                rsig = (j0 + 0 < nv) ? rsig : 0.f;
                accM = __builtin_fmaf(rsig, d0 - mu, accM);

                mu = t11 * 0.015625f;
                var = __builtin_fmaf(t21, 0.015625f, -mu * mu);
                var = var > 0.f ? var : 0.f;
                rsig = __frsqrt_rn(var + LN_EPS);
                rsig = (j0 + 1 < nv) ? rsig : 0.f;
                accM = __builtin_fmaf(rsig, d1 - mu, accM);

                mu = t12 * 0.015625f;
                var = __builtin_fmaf(t22, 0.015625f, -mu * mu);
                var = var > 0.f ? var : 0.f;
                rsig = __frsqrt_rn(var + LN_EPS);
                rsig = (j0 + 2 < nv) ? rsig : 0.f;
                accM = __builtin_fmaf(rsig, d2 - mu, accM);

                mu = t13 * 0.015625f;
                var = __builtin_fmaf(t23, 0.015625f, -mu * mu);
                var = var > 0.f ? var : 0.f;
                rsig = __frsqrt_rn(var + LN_EPS);
                rsig = (j0 + 3 < nv) ? rsig : 0.f;
                accM = __builtin_fmaf(rsig, d3 - mu, accM);

                hv0 = hn0; hv1 = hn1; hv2 = hn2; hv3 = hn3;
            }
        }

        const float nfn = nf[n];
        const float av  = nfn * __builtin_fmaf(g, accM, b * (float)sigma);

        // p[lane] = sum_k av(lane k) * G[k][lane] via readlane broadcast
        float p = 0.f;
        const int avi = __float_as_int(av);
#pragma unroll
        for (int k = 0; k < 64; ++k) {
            float ak = __int_as_float(__builtin_amdgcn_readlane(avi, k));
            p = __builtin_fmaf(ak, Gs[k * 64 + lane], p);
        }

        const float yv = -ALPHA * p + (1.0f - ALPHA) * y[n * 64 + lane];
        y[n * 64 + lane] = yv;
        s[n * 64 + lane] = (1.0f - ALPHA) * s[n * 64 + lane] + av;
        if (!last) hnxt[n * 64 + lane] = nfn * (yv + xU[n * 64 + lane]);
    }
}

// ---------------------------------------------------------------------------
// final: z = -alpha*(s@W) ; zf = nf*z + xh ; out = zf@Wlast^T + blast
// ---------------------------------------------------------------------------
__global__ __launch_bounds__(256) void final_out(
        const float* __restrict__ s, const float* __restrict__ xh,
        const float* __restrict__ nf, const float* __restrict__ W,
        const float* __restrict__ Wlast, const float* __restrict__ blast,
        float* __restrict__ out) {
    __shared__ float Ws[64 * 64];
    __shared__ float WlT[64 * OUTC];
    __shared__ float blS[OUTC];
    __shared__ float ss[4][64];
    __shared__ float zfs[4][64];
    for (int t = threadIdx.x; t < 64 * 64; t += 256) Ws[t] = W[t];
    for (int t = threadIdx.x; t < OUTC * 64; t += 256) {
        int o = t >> 6, j = t & 63;
        WlT[j * OUTC + o] = Wlast[t];
    }
    if (threadIdx.x < OUTC) blS[threadIdx.x] = blast[threadIdx.x];
    __syncthreads();
    int lane = threadIdx.x & 63, wv = threadIdx.x >> 6;
    for (int n0 = blockIdx.x * 4; n0 < NN; n0 += gridDim.x * 4) {
        int n = n0 + wv;
        if (n < NN) ss[wv][lane] = s[n * 64 + lane];
        __syncthreads();
        if (n < NN) {
            float z = 0.f;
#pragma unroll 8
            for (int k = 0; k < 64; ++k) z += ss[wv][k] * Ws[k * 64 + lane];
            z *= -ALPHA;
            zfs[wv][lane] = nf[n] * z + xh[n * 64 + lane];
        }
        __syncthreads();
        if (n < NN && lane < OUTC) {
            float acc = blS[lane];
#pragma unroll 8
            for (int j = 0; j < 64; ++j) acc += zfs[wv][j] * WlT[j * OUTC + lane];
            out[n * OUTC + lane] = acc;
        }
        __syncthreads();
    }
}

// ---------------------------------------------------------------------------
extern "C" void kernel_launch(void* const* d_in, const int* in_sizes, int n_in,
                              void* d_out, int out_size, void* d_ws, size_t ws_size,
                              hipStream_t stream) {
    const float* x     = (const float*)d_in[0];
    const int*   ei    = (const int*)  d_in[1];
    const float* nf    = (const float*)d_in[2];
    const float* We    = (const float*)d_in[3];
    const float* be    = (const float*)d_in[4];
    const float* W     = (const float*)d_in[5];
    const float* U     = (const float*)d_in[6];
    const float* bU    = (const float*)d_in[7];
    const float* gamma = (const float*)d_in[8];
    const float* beta  = (const float*)d_in[9];
    const float* Wlast = (const float*)d_in[10];
    const float* blast = (const float*)d_in[11];
    float* out = (float*)d_out;

    char* ws = (char*)d_ws;
    size_t off = 0;
    const size_t NH = (size_t)NN * HH * sizeof(float);
    int*   adj    = (int*)(ws + off);            off += (size_t)2 * EE * sizeof(int);
    unsigned short* rank16 = (unsigned short*)(ws + off);
                                                 off += (size_t)2 * EE * sizeof(unsigned short);
    int*   offs   = (int*)(ws + off);            off += (size_t)NN * sizeof(int);
    int*   cnt    = (int*)(ws + off);            off += (size_t)NN * sizeof(int);
    int*   bsum   = (int*)(ws + off);            off += 256 * sizeof(int);
    float* xh     = (float*)(ws + off);          off += NH;
    float* xU     = (float*)(ws + off);          off += NH;
    float* h0     = (float*)(ws + off);          off += NH;
    float* h1     = (float*)(ws + off);          off += NH;
    float* y      = (float*)(ws + off);          off += NH;
    float* s      = (float*)(ws + off);          off += NH;
    float* G      = (float*)(ws + off);          off += (size_t)HH * HH * sizeof(float);

    hipMemsetAsync(cnt, 0, (size_t)NN * sizeof(int), stream);
    hipMemsetAsync(y, 0, 2 * NH, stream);   // y and s are adjacent

    // CSR build (once per launch): atomic count (+rank capture), scan,
    // atomic-free fill.
    csr_count<<<(2 * EE + 255) / 256, 256, 0, stream>>>(ei, cnt, rank16);
    scanA<<<NB_SCAN, 256, 0, stream>>>(cnt, offs, bsum);
    scanB<<<1, 256, 0, stream>>>(bsum);
    scanC<<<NB_SCAN, 256, 0, stream>>>(offs, bsum);
    csr_fill<<<(2 * EE + 255) / 256, 256, 0, stream>>>(ei, offs, rank16, adj);

    make_G<<<1, 256, 0, stream>>>(W, G);
    extractor<<<2048, 256, 0, stream>>>(x, nf, We, be, U, bU, xh, xU, h0);

    float* hc = h0;
    float* hn = h1;
    for (int t = 0; t < 4; ++t) {
        fused_step<<<2048, 256, 0, stream>>>(adj, offs, cnt, hc, hn, nf,
                                             gamma, beta, G, xU, y, s, t == 3);
        float* tmp = hc; hc = hn; hn = tmp;
    }
    final_out<<<2048, 256, 0, stream>>>(s, xh, nf, W, Wlast, blast, out);
}

// Round 11
// 1407.158 us; speedup vs baseline: 1.8260x; 1.0875x over previous
//
#include <hip/hip_runtime.h>
#include <hip/hip_bf16.h>

// Problem constants (from reference)
#define NN   50000
#define EE   1600000
#define INC  128
#define HH   64
#define OUTC 40
#define ALPHA 0.8f
#define LN_EPS 1e-5f
#define NB_SCAN 196   // ceil(NN/256)

// ---------------------------------------------------------------------------
// Wave64 sum via fused v_add_f32_dpp (inline asm; 1 inst/stage guaranteed).
// 8 independent chains interleaved (also satisfies DPP wait-states).
// Total lands in lane 63.
// ---------------------------------------------------------------------------
#define DPP8(CTRL)                                                             \
    asm volatile(                                                              \
        "v_add_f32_dpp %0, %0, %0 " CTRL "\n\t"                                \
        "v_add_f32_dpp %1, %1, %1 " CTRL "\n\t"                                \
        "v_add_f32_dpp %2, %2, %2 " CTRL "\n\t"                                \
        "v_add_f32_dpp %3, %3, %3 " CTRL "\n\t"                                \
        "v_add_f32_dpp %4, %4, %4 " CTRL "\n\t"                                \
        "v_add_f32_dpp %5, %5, %5 " CTRL "\n\t"                                \
        "v_add_f32_dpp %6, %6, %6 " CTRL "\n\t"                                \
        "v_add_f32_dpp %7, %7, %7 " CTRL                                       \
        : "+v"(s0), "+v"(s1), "+v"(s2), "+v"(s3),                              \
          "+v"(s4), "+v"(s5), "+v"(s6), "+v"(s7))

#define DPP_ALL6()                                                             \
    DPP8("row_shr:1 row_mask:0xf bank_mask:0xf bound_ctrl:0");                 \
    DPP8("row_shr:2 row_mask:0xf bank_mask:0xf bound_ctrl:0");                 \
    DPP8("row_shr:4 row_mask:0xf bank_mask:0xf bound_ctrl:0");                 \
    DPP8("row_shr:8 row_mask:0xf bank_mask:0xf bound_ctrl:0");                 \
    DPP8("row_bcast:15 row_mask:0xa bank_mask:0xf bound_ctrl:0");              \
    DPP8("row_bcast:31 row_mask:0xc bank_mask:0xf bound_ctrl:0")

__device__ __forceinline__ float rl63(float x) {
    return __int_as_float(__builtin_amdgcn_readlane(__float_as_int(x), 63));
}

__device__ __forceinline__ float fast_tanh(float x) {
    float e = __builtin_amdgcn_exp2f(-2.8853900817779268f * __builtin_fabsf(x));
    float t = (1.0f - e) * __builtin_amdgcn_rcpf(1.0f + e);
    return __builtin_copysignf(t, x);
}

// one quad (4 edges) of message accumulation: returns sum_i rsig_i*(d_i-mu_i).
// GUARD=true applies the tail-validity mask (j0+i < nv).
template <bool GUARD>
__device__ __forceinline__ float quad_contrib(float hn, float hv0, float hv1,
                                              float hv2, float hv3,
                                              int j0, int nv) {
    float d0 = fast_tanh(hn - hv0);
    float d1 = fast_tanh(hn - hv1);
    float d2 = fast_tanh(hn - hv2);
    float d3 = fast_tanh(hn - hv3);
    float s0 = d0, s1 = d1, s2 = d2, s3 = d3;
    float s4 = d0 * d0, s5 = d1 * d1, s6 = d2 * d2, s7 = d3 * d3;
    DPP_ALL6();
    float t10 = rl63(s0), t11 = rl63(s1), t12 = rl63(s2), t13 = rl63(s3);
    float t20 = rl63(s4), t21 = rl63(s5), t22 = rl63(s6), t23 = rl63(s7);

    float acc = 0.f, mu, var, rsig;
    mu = t10 * 0.015625f;
    var = __builtin_fmaf(t20, 0.015625f, -mu * mu);
    var = var > 0.f ? var : 0.f;
    rsig = __frsqrt_rn(var + LN_EPS);
    if (GUARD) rsig = (j0 + 0 < nv) ? rsig : 0.f;
    acc = __builtin_fmaf(rsig, d0 - mu, acc);

    mu = t11 * 0.015625f;
    var = __builtin_fmaf(t21, 0.015625f, -mu * mu);
    var = var > 0.f ? var : 0.f;
    rsig = __frsqrt_rn(var + LN_EPS);
    if (GUARD) rsig = (j0 + 1 < nv) ? rsig : 0.f;
    acc = __builtin_fmaf(rsig, d1 - mu, acc);

    mu = t12 * 0.015625f;
    var = __builtin_fmaf(t22, 0.015625f, -mu * mu);
    var = var > 0.f ? var : 0.f;
    rsig = __frsqrt_rn(var + LN_EPS);
    if (GUARD) rsig = (j0 + 2 < nv) ? rsig : 0.f;
    acc = __builtin_fmaf(rsig, d2 - mu, acc);

    mu = t13 * 0.015625f;
    var = __builtin_fmaf(t23, 0.015625f, -mu * mu);
    var = var > 0.f ? var : 0.f;
    rsig = __frsqrt_rn(var + LN_EPS);
    if (GUARD) rsig = (j0 + 3 < nv) ? rsig : 0.f;
    acc = __builtin_fmaf(rsig, d3 - mu, acc);
    return acc;
}

// ---------------------------------------------------------------------------
// CSR build, atomic-light (R10): count returns per-node rank; fill is
// atomic-free scattered stores (L2-absorbed).
// ---------------------------------------------------------------------------
__global__ __launch_bounds__(256) void csr_count(const int* __restrict__ ei,
                                                 int* __restrict__ cnt,
                                                 unsigned short* __restrict__ rank16) {
    int i = blockIdx.x * 256 + threadIdx.x;
    if (i >= 2 * EE) return;
    int r = atomicAdd(&cnt[ei[i]], 1);
    rank16[i] = (unsigned short)r;
}

__global__ __launch_bounds__(256) void scanA(const int* __restrict__ cnt,
                                             int* __restrict__ offs,
                                             int* __restrict__ bsum) {
    __shared__ int tmp[256];
    int i = blockIdx.x * 256 + threadIdx.x;
    int v = (i < NN) ? cnt[i] : 0;
    tmp[threadIdx.x] = v;
    __syncthreads();
    int acc = v;
    for (int d = 1; d < 256; d <<= 1) {
        int t = (threadIdx.x >= d) ? tmp[threadIdx.x - d] : 0;
        __syncthreads();
        acc += t;
        tmp[threadIdx.x] = acc;
        __syncthreads();
    }
    if (i < NN) offs[i] = acc - v;
    if (threadIdx.x == 255) bsum[blockIdx.x] = acc;
}

__global__ __launch_bounds__(256) void scanB(int* __restrict__ bsum) {
    __shared__ int tmp[256];
    int v = (threadIdx.x < NB_SCAN) ? bsum[threadIdx.x] : 0;
    tmp[threadIdx.x] = v;
    __syncthreads();
    int acc = v;
    for (int d = 1; d < 256; d <<= 1) {
        int t = (threadIdx.x >= d) ? tmp[threadIdx.x - d] : 0;
        __syncthreads();
        acc += t;
        tmp[threadIdx.x] = acc;
        __syncthreads();
    }
    if (threadIdx.x < NB_SCAN) bsum[threadIdx.x] = acc - v;
}

__global__ __launch_bounds__(256) void scanC(int* __restrict__ offs,
                                             const int* __restrict__ bsum) {
    int i = blockIdx.x * 256 + threadIdx.x;
    if (i < NN) offs[i] += bsum[blockIdx.x];
}

__global__ __launch_bounds__(256) void csr_fill(const int* __restrict__ ei,
                                                const int* __restrict__ offs,
                                                const unsigned short* __restrict__ rank16,
                                                int* __restrict__ adj) {
    int i = blockIdx.x * 256 + threadIdx.x;
    if (i >= 2 * EE) return;
    int node  = ei[i];
    int role  = (i >= EE) ? 1 : 0;
    int other = role ? ei[i - EE] : ei[i + EE];
    adj[offs[node] + (int)rank16[i]] = other | (role << 31);
}

// ---------------------------------------------------------------------------
// G = W @ W^T  (64x64). One block.
// ---------------------------------------------------------------------------
__global__ __launch_bounds__(256) void make_G(const float* __restrict__ W,
                                              float* __restrict__ G) {
    __shared__ float Ws[64 * 64];
    for (int t = threadIdx.x; t < 64 * 64; t += 256) Ws[t] = W[t];
    __syncthreads();
    for (int t = threadIdx.x; t < 64 * 64; t += 256) {
        int i = t >> 6, j = t & 63;
        float acc = 0.f;
#pragma unroll 8
        for (int k = 0; k < 64; ++k) acc += Ws[i * 64 + k] * Ws[j * 64 + k];
        G[t] = acc;
    }
}

// ---------------------------------------------------------------------------
// extractor: xh = x@We^T + be ; h0 = xh@U^T + bU ; xU = h0 / nf
// ---------------------------------------------------------------------------
__global__ __launch_bounds__(256) void extractor(
        const float* __restrict__ x, const float* __restrict__ nf,
        const float* __restrict__ We, const float* __restrict__ be,
        const float* __restrict__ U,  const float* __restrict__ bU,
        float* __restrict__ xh, float* __restrict__ xU, float* __restrict__ h0) {
    __shared__ float WeT[INC * HH];
    __shared__ float UT[HH * HH];
    __shared__ float beS[HH], bUS[HH];
    __shared__ float xs[4][INC];
    __shared__ float xhs[4][HH];

    for (int t = threadIdx.x; t < INC * HH; t += 256) {
        int j = t >> 7, k = t & 127;
        WeT[k * 64 + j] = We[t];
    }
    for (int t = threadIdx.x; t < HH * HH; t += 256) {
        int j = t >> 6, k = t & 63;
        UT[k * 64 + j] = U[t];
    }
    if (threadIdx.x < 64) { beS[threadIdx.x] = be[threadIdx.x]; bUS[threadIdx.x] = bU[threadIdx.x]; }
    __syncthreads();

    int lane = threadIdx.x & 63;
    int wv   = threadIdx.x >> 6;

    for (int n0 = blockIdx.x * 4; n0 < NN; n0 += gridDim.x * 4) {
        int n = n0 + wv;
        bool valid = n < NN;
        if (valid) {
            xs[wv][lane]      = x[(size_t)n * INC + lane];
            xs[wv][lane + 64] = x[(size_t)n * INC + lane + 64];
        }
        __syncthreads();
        float acc = beS[lane];
        if (valid) {
#pragma unroll 8
            for (int k = 0; k < INC; ++k) acc += xs[wv][k] * WeT[k * 64 + lane];
            xh[n * 64 + lane] = acc;
            xhs[wv][lane] = acc;
        }
        __syncthreads();
        if (valid) {
            float acc2 = bUS[lane];
#pragma unroll 8
            for (int k = 0; k < HH; ++k) acc2 += xhs[wv][k] * UT[k * 64 + lane];
            h0[n * 64 + lane] = acc2;
            xU[n * 64 + lane] = acc2 / nf[n];
        }
        __syncthreads();
    }
}

// ---------------------------------------------------------------------------
// fused step v5: per node n (one wave, lane = channel).
// base/deg forced into SGPRs via readfirstlane -> all control/index math is
// SALU. Full 64-edge chunks run a fully-unrolled 16-quad loop with LITERAL
// readlane indices, wraparound prefetch, no clamps/guards; the remainder
// chunk (deg&63) uses the guarded path. No atomics.
// ---------------------------------------------------------------------------
__global__ __launch_bounds__(256) void fused_step(
        const int* __restrict__ adj, const int* __restrict__ offs,
        const int* __restrict__ cnt,
        const float* __restrict__ hcur, float* __restrict__ hnxt,
        const float* __restrict__ nf, const float* __restrict__ gamma,
        const float* __restrict__ beta, const float* __restrict__ Gm,
        const float* __restrict__ xU,
        float* __restrict__ y, float* __restrict__ s, int last) {
    __shared__ float Gs[64 * 64];
    for (int t = threadIdx.x; t < 64 * 64; t += 256) Gs[t] = Gm[t];
    __syncthreads();

    const int lane = threadIdx.x & 63, wv = threadIdx.x >> 6;
    const float g = gamma[lane], b = beta[lane];

    for (int n = blockIdx.x * 4 + wv; n < NN; n += gridDim.x * 4) {
        const int base = __builtin_amdgcn_readfirstlane(offs[n]);
        const int deg  = __builtin_amdgcn_readfirstlane(cnt[n]);
        const float hn = hcur[(size_t)n * 64 + lane];
        float accM = 0.f;
        int sigma = 0;

        // ---- full 64-edge chunks: clamp-free, literal lane indices
        const int nfull = deg >> 6;
        for (int c = 0; c < nfull; ++c) {
            const int ev = adj[base + (c << 6) + lane];
            sigma += 64 - 2 * (int)__builtin_popcountll(__ballot(ev < 0));

            float hv0, hv1, hv2, hv3;
            {
                int e0 = __builtin_amdgcn_readlane(ev, 0);
                int e1 = __builtin_amdgcn_readlane(ev, 1);
                int e2 = __builtin_amdgcn_readlane(ev, 2);
                int e3 = __builtin_amdgcn_readlane(ev, 3);
                hv0 = hcur[(size_t)((unsigned)e0 & 0x7fffffffu) * 64u + lane];
                hv1 = hcur[(size_t)((unsigned)e1 & 0x7fffffffu) * 64u + lane];
                hv2 = hcur[(size_t)((unsigned)e2 & 0x7fffffffu) * 64u + lane];
                hv3 = hcur[(size_t)((unsigned)e3 & 0x7fffffffu) * 64u + lane];
            }
#pragma unroll
            for (int q = 0; q < 16; ++q) {
                const int j0 = q << 2;
                // wraparound prefetch: at q=15 re-loads edges 0..3 (discarded)
                int e0 = __builtin_amdgcn_readlane(ev, (j0 + 4) & 63);
                int e1 = __builtin_amdgcn_readlane(ev, (j0 + 5) & 63);
                int e2 = __builtin_amdgcn_readlane(ev, (j0 + 6) & 63);
                int e3 = __builtin_amdgcn_readlane(ev, (j0 + 7) & 63);
                float n0 = hcur[(size_t)((unsigned)e0 & 0x7fffffffu) * 64u + lane];
                float n1 = hcur[(size_t)((unsigned)e1 & 0x7fffffffu) * 64u + lane];
                float n2 = hcur[(size_t)((unsigned)e2 & 0x7fffffffu) * 64u + lane];
                float n3 = hcur[(size_t)((unsigned)e3 & 0x7fffffffu) * 64u + lane];

                accM += quad_contrib<false>(hn, hv0, hv1, hv2, hv3, 0, 64);

                hv0 = n0; hv1 = n1; hv2 = n2; hv3 = n3;
            }
        }

        // ---- remainder chunk (deg & 63 edges), guarded
        const int rem = deg & 63;
        if (rem) {
            const int rbase = base + (nfull << 6);
            int li = lane < rem ? lane : rem - 1;
            int ev = adj[rbase + li];
            unsigned long long bal = __ballot(ev < 0);
            unsigned long long msk = (1ull << rem) - 1ull;
            sigma += rem - 2 * (int)__builtin_popcountll(bal & msk);

            float hv0, hv1, hv2, hv3;
            {
                int j1 = 1 < rem ? 1 : rem - 1;
                int j2 = 2 < rem ? 2 : rem - 1;
                int j3 = 3 < rem ? 3 : rem - 1;
                int e0 = __builtin_amdgcn_readlane(ev, 0);
                int e1 = __builtin_amdgcn_readlane(ev, j1);
                int e2 = __builtin_amdgcn_readlane(ev, j2);
                int e3 = __builtin_amdgcn_readlane(ev, j3);
                hv0 = hcur[(size_t)((unsigned)e0 & 0x7fffffffu) * 64u + lane];
                hv1 = hcur[(size_t)((unsigned)e1 & 0x7fffffffu) * 64u + lane];
                hv2 = hcur[(size_t)((unsigned)e2 & 0x7fffffffu) * 64u + lane];
                hv3 = hcur[(size_t)((unsigned)e3 & 0x7fffffffu) * 64u + lane];
            }
            const int quads = (rem + 3) >> 2;
            for (int q = 0; q < quads; ++q) {
                const int j0 = q << 2;
                int ja = j0 + 4; ja = ja < rem ? ja : rem - 1;
                int jb = j0 + 5; jb = jb < rem ? jb : rem - 1;
                int jc = j0 + 6; jc = jc < rem ? jc : rem - 1;
                int jd = j0 + 7; jd = jd < rem ? jd : rem - 1;
                int e0 = __builtin_amdgcn_readlane(ev, ja);
                int e1 = __builtin_amdgcn_readlane(ev, jb);
                int e2 = __builtin_amdgcn_readlane(ev, jc);
                int e3 = __builtin_amdgcn_readlane(ev, jd);
                float n0 = hcur[(size_t)((unsigned)e0 & 0x7fffffffu) * 64u + lane];
                float n1 = hcur[(size_t)((unsigned)e1 & 0x7fffffffu) * 64u + lane];
                float n2 = hcur[(size_t)((unsigned)e2 & 0x7fffffffu) * 64u + lane];
                float n3 = hcur[(size_t)((unsigned)e3 & 0x7fffffffu) * 64u + lane];

                accM += quad_contrib<true>(hn, hv0, hv1, hv2, hv3, j0, rem);

                hv0 = n0; hv1 = n1; hv2 = n2; hv3 = n3;
            }
        }

        const float nfn = nf[n];
        const float av  = nfn * __builtin_fmaf(g, accM, b * (float)sigma);

        // p[lane] = sum_k av(lane k) * G[k][lane] via readlane broadcast
        float p = 0.f;
        const int avi = __float_as_int(av);
#pragma unroll
        for (int k = 0; k < 64; ++k) {
            float ak = __int_as_float(__builtin_amdgcn_readlane(avi, k));
            p = __builtin_fmaf(ak, Gs[k * 64 + lane], p);
        }

        const float yv = -ALPHA * p + (1.0f - ALPHA) * y[n * 64 + lane];
        y[n * 64 + lane] = yv;
        s[n * 64 + lane] = (1.0f - ALPHA) * s[n * 64 + lane] + av;
        if (!last) hnxt[n * 64 + lane] = nfn * (yv + xU[n * 64 + lane]);
    }
}

// ---------------------------------------------------------------------------
// final: z = -alpha*(s@W) ; zf = nf*z + xh ; out = zf@Wlast^T + blast
// ---------------------------------------------------------------------------
__global__ __launch_bounds__(256) void final_out(
        const float* __restrict__ s, const float* __restrict__ xh,
        const float* __restrict__ nf, const float* __restrict__ W,
        const float* __restrict__ Wlast, const float* __restrict__ blast,
        float* __restrict__ out) {
    __shared__ float Ws[64 * 64];
    __shared__ float WlT[64 * OUTC];
    __shared__ float blS[OUTC];
    __shared__ float ss[4][64];
    __shared__ float zfs[4][64];
    for (int t = threadIdx.x; t < 64 * 64; t += 256) Ws[t] = W[t];
    for (int t = threadIdx.x; t < OUTC * 64; t += 256) {
        int o = t >> 6, j = t & 63;
        WlT[j * OUTC + o] = Wlast[t];
    }
    if (threadIdx.x < OUTC) blS[threadIdx.x] = blast[threadIdx.x];
    __syncthreads();
    int lane = threadIdx.x & 63, wv = threadIdx.x >> 6;
    for (int n0 = blockIdx.x * 4; n0 < NN; n0 += gridDim.x * 4) {
        int n = n0 + wv;
        if (n < NN) ss[wv][lane] = s[n * 64 + lane];
        __syncthreads();
        if (n < NN) {
            float z = 0.f;
#pragma unroll 8
            for (int k = 0; k < 64; ++k) z += ss[wv][k] * Ws[k * 64 + lane];
            z *= -ALPHA;
            zfs[wv][lane] = nf[n] * z + xh[n * 64 + lane];
        }
        __syncthreads();
        if (n < NN && lane < OUTC) {
            float acc = blS[lane];
#pragma unroll 8
            for (int j = 0; j < 64; ++j) acc += zfs[wv][j] * WlT[j * OUTC + lane];
            out[n * OUTC + lane] = acc;
        }
        __syncthreads();
    }
}

// ---------------------------------------------------------------------------
extern "C" void kernel_launch(void* const* d_in, const int* in_sizes, int n_in,
                              void* d_out, int out_size, void* d_ws, size_t ws_size,
                              hipStream_t stream) {
    const float* x     = (const float*)d_in[0];
    const int*   ei    = (const int*)  d_in[1];
    const float* nf    = (const float*)d_in[2];
    const float* We    = (const float*)d_in[3];
    const float* be    = (const float*)d_in[4];
    const float* W     = (const float*)d_in[5];
    const float* U     = (const float*)d_in[6];
    const float* bU    = (const float*)d_in[7];
    const float* gamma = (const float*)d_in[8];
    const float* beta  = (const float*)d_in[9];
    const float* Wlast = (const float*)d_in[10];
    const float* blast = (const float*)d_in[11];
    float* out = (float*)d_out;

    char* ws = (char*)d_ws;
    size_t off = 0;
    const size_t NH = (size_t)NN * HH * sizeof(float);
    int*   adj    = (int*)(ws + off);            off += (size_t)2 * EE * sizeof(int);
    unsigned short* rank16 = (unsigned short*)(ws + off);
                                                 off += (size_t)2 * EE * sizeof(unsigned short);
    int*   offs   = (int*)(ws + off);            off += (size_t)NN * sizeof(int);
    int*   cnt    = (int*)(ws + off);            off += (size_t)NN * sizeof(int);
    int*   bsum   = (int*)(ws + off);            off += 256 * sizeof(int);
    float* xh     = (float*)(ws + off);          off += NH;
    float* xU     = (float*)(ws + off);          off += NH;
    float* h0     = (float*)(ws + off);          off += NH;
    float* h1     = (float*)(ws + off);          off += NH;
    float* y      = (float*)(ws + off);          off += NH;
    float* s      = (float*)(ws + off);          off += NH;
    float* G      = (float*)(ws + off);          off += (size_t)HH * HH * sizeof(float);

    hipMemsetAsync(cnt, 0, (size_t)NN * sizeof(int), stream);
    hipMemsetAsync(y, 0, 2 * NH, stream);   // y and s are adjacent

    // CSR build (once per launch): atomic count (+rank capture), scan,
    // atomic-free fill.
    csr_count<<<(2 * EE + 255) / 256, 256, 0, stream>>>(ei, cnt, rank16);
    scanA<<<NB_SCAN, 256, 0, stream>>>(cnt, offs, bsum);
    scanB<<<1, 256, 0, stream>>>(bsum);
    scanC<<<NB_SCAN, 256, 0, stream>>>(offs, bsum);
    csr_fill<<<(2 * EE + 255) / 256, 256, 0, stream>>>(ei, offs, rank16, adj);

    make_G<<<1, 256, 0, stream>>>(W, G);
    extractor<<<2048, 256, 0, stream>>>(x, nf, We, be, U, bU, xh, xU, h0);

    float* hc = h0;
    float* hn = h1;
    for (int t = 0; t < 4; ++t) {
        fused_step<<<2048, 256, 0, stream>>>(adj, offs, cnt, hc, hn, nf,
                                             gamma, beta, G, xU, y, s, t == 3);
        float* tmp = hc; hc = hn; hn = tmp;
    }
    final_out<<<2048, 256, 0, stream>>>(s, xh, nf, W, Wlast, blast, out);
}

// Round 12
// 1338.620 us; speedup vs baseline: 1.9195x; 1.0512x over previous
//
#include <hip/hip_runtime.h>
#include <hip/hip_bf16.h>

// Problem constants (from reference)
#define NN   50000
#define EE   1600000
#define INC  128
#define HH   64
#define OUTC 40
#define ALPHA 0.8f
#define LN_EPS 1e-5f
#define NB_SCAN 196   // ceil(NN/256)

// ---------------------------------------------------------------------------
// Wave64 sum via fused v_add_f32_dpp (inline asm; 1 inst/stage guaranteed).
// 8 independent chains interleaved (also satisfies DPP wait-states).
// Total lands in lane 63.
// ---------------------------------------------------------------------------
#define DPP8(CTRL)                                                             \
    asm volatile(                                                              \
        "v_add_f32_dpp %0, %0, %0 " CTRL "\n\t"                                \
        "v_add_f32_dpp %1, %1, %1 " CTRL "\n\t"                                \
        "v_add_f32_dpp %2, %2, %2 " CTRL "\n\t"                                \
        "v_add_f32_dpp %3, %3, %3 " CTRL "\n\t"                                \
        "v_add_f32_dpp %4, %4, %4 " CTRL "\n\t"                                \
        "v_add_f32_dpp %5, %5, %5 " CTRL "\n\t"                                \
        "v_add_f32_dpp %6, %6, %6 " CTRL "\n\t"                                \
        "v_add_f32_dpp %7, %7, %7 " CTRL                                       \
        : "+v"(s0), "+v"(s1), "+v"(s2), "+v"(s3),                              \
          "+v"(s4), "+v"(s5), "+v"(s6), "+v"(s7))

#define DPP_ALL6()                                                             \
    DPP8("row_shr:1 row_mask:0xf bank_mask:0xf bound_ctrl:0");                 \
    DPP8("row_shr:2 row_mask:0xf bank_mask:0xf bound_ctrl:0");                 \
    DPP8("row_shr:4 row_mask:0xf bank_mask:0xf bound_ctrl:0");                 \
    DPP8("row_shr:8 row_mask:0xf bank_mask:0xf bound_ctrl:0");                 \
    DPP8("row_bcast:15 row_mask:0xa bank_mask:0xf bound_ctrl:0");              \
    DPP8("row_bcast:31 row_mask:0xc bank_mask:0xf bound_ctrl:0")

__device__ __forceinline__ float rl63(float x) {
    return __int_as_float(__builtin_amdgcn_readlane(__float_as_int(x), 63));
}

// tanh(x) = 1 - 2/(1 + 2^(2*log2(e)*x))  — signed arg, no abs/copysign.
// x->-inf: e->0, u->1, d->-1. x->+inf: e->inf, u->0, d->+1. rcp(inf)=0 safe.
__device__ __forceinline__ float fast_tanh_s(float x) {
    float e = __builtin_amdgcn_exp2f(2.8853900817779268f * x);
    float u = __builtin_amdgcn_rcpf(1.0f + e);
    return __builtin_fmaf(-2.0f, u, 1.0f);
}

// one quad (4 edges): returns sum_i rsig_i*(d_i-mu_i).
// GUARD=true applies the tail-validity mask (j0+i < nv).
template <bool GUARD>
__device__ __forceinline__ float quad_contrib(float hn, float hv0, float hv1,
                                              float hv2, float hv3,
                                              int j0, int nv) {
    float d0 = fast_tanh_s(hn - hv0);
    float d1 = fast_tanh_s(hn - hv1);
    float d2 = fast_tanh_s(hn - hv2);
    float d3 = fast_tanh_s(hn - hv3);
    float s0 = d0, s1 = d1, s2 = d2, s3 = d3;
    float s4 = d0 * d0, s5 = d1 * d1, s6 = d2 * d2, s7 = d3 * d3;
    DPP_ALL6();
    float t10 = rl63(s0), t11 = rl63(s1), t12 = rl63(s2), t13 = rl63(s3);
    float t20 = rl63(s4), t21 = rl63(s5), t22 = rl63(s6), t23 = rl63(s7);

    float acc = 0.f, mu, var, rsig;
    // var+eps folded: v = fma(t2,1/64, fma(-mu,mu,eps)); clamp below at eps.
    mu  = t10 * 0.015625f;
    var = __builtin_fmaf(t20, 0.015625f, __builtin_fmaf(-mu, mu, LN_EPS));
    var = var > LN_EPS ? var : LN_EPS;
    rsig = __frsqrt_rn(var);
    if (GUARD) rsig = (j0 + 0 < nv) ? rsig : 0.f;
    acc = __builtin_fmaf(rsig, d0 - mu, acc);

    mu  = t11 * 0.015625f;
    var = __builtin_fmaf(t21, 0.015625f, __builtin_fmaf(-mu, mu, LN_EPS));
    var = var > LN_EPS ? var : LN_EPS;
    rsig = __frsqrt_rn(var);
    if (GUARD) rsig = (j0 + 1 < nv) ? rsig : 0.f;
    acc = __builtin_fmaf(rsig, d1 - mu, acc);

    mu  = t12 * 0.015625f;
    var = __builtin_fmaf(t22, 0.015625f, __builtin_fmaf(-mu, mu, LN_EPS));
    var = var > LN_EPS ? var : LN_EPS;
    rsig = __frsqrt_rn(var);
    if (GUARD) rsig = (j0 + 2 < nv) ? rsig : 0.f;
    acc = __builtin_fmaf(rsig, d2 - mu, acc);

    mu  = t13 * 0.015625f;
    var = __builtin_fmaf(t23, 0.015625f, __builtin_fmaf(-mu, mu, LN_EPS));
    var = var > LN_EPS ? var : LN_EPS;
    rsig = __frsqrt_rn(var);
    if (GUARD) rsig = (j0 + 3 < nv) ? rsig : 0.f;
    acc = __builtin_fmaf(rsig, d3 - mu, acc);
    return acc;
}

// ---------------------------------------------------------------------------
// CSR build, atomic-light (R10): count returns per-node rank; fill is
// atomic-free scattered stores (L2-absorbed).
// ---------------------------------------------------------------------------
__global__ __launch_bounds__(256) void csr_count(const int* __restrict__ ei,
                                                 int* __restrict__ cnt,
                                                 unsigned short* __restrict__ rank16) {
    int i = blockIdx.x * 256 + threadIdx.x;
    if (i >= 2 * EE) return;
    int r = atomicAdd(&cnt[ei[i]], 1);
    rank16[i] = (unsigned short)r;
}

__global__ __launch_bounds__(256) void scanA(const int* __restrict__ cnt,
                                             int* __restrict__ offs,
                                             int* __restrict__ bsum) {
    __shared__ int tmp[256];
    int i = blockIdx.x * 256 + threadIdx.x;
    int v = (i < NN) ? cnt[i] : 0;
    tmp[threadIdx.x] = v;
    __syncthreads();
    int acc = v;
    for (int d = 1; d < 256; d <<= 1) {
        int t = (threadIdx.x >= d) ? tmp[threadIdx.x - d] : 0;
        __syncthreads();
        acc += t;
        tmp[threadIdx.x] = acc;
        __syncthreads();
    }
    if (i < NN) offs[i] = acc - v;
    if (threadIdx.x == 255) bsum[blockIdx.x] = acc;
}

__global__ __launch_bounds__(256) void scanB(int* __restrict__ bsum) {
    __shared__ int tmp[256];
    int v = (threadIdx.x < NB_SCAN) ? bsum[threadIdx.x] : 0;
    tmp[threadIdx.x] = v;
    __syncthreads();
    int acc = v;
    for (int d = 1; d < 256; d <<= 1) {
        int t = (threadIdx.x >= d) ? tmp[threadIdx.x - d] : 0;
        __syncthreads();
        acc += t;
        tmp[threadIdx.x] = acc;
        __syncthreads();
    }
    if (threadIdx.x < NB_SCAN) bsum[threadIdx.x] = acc - v;
}

__global__ __launch_bounds__(256) void scanC(int* __restrict__ offs,
                                             const int* __restrict__ bsum) {
    int i = blockIdx.x * 256 + threadIdx.x;
    if (i < NN) offs[i] += bsum[blockIdx.x];
}

__global__ __launch_bounds__(256) void csr_fill(const int* __restrict__ ei,
                                                const int* __restrict__ offs,
                                                const unsigned short* __restrict__ rank16,
                                                int* __restrict__ adj) {
    int i = blockIdx.x * 256 + threadIdx.x;
    if (i >= 2 * EE) return;
    int node  = ei[i];
    int role  = (i >= EE) ? 1 : 0;
    int other = role ? ei[i - EE] : ei[i + EE];
    adj[offs[node] + (int)rank16[i]] = other | (role << 31);
}

// ---------------------------------------------------------------------------
// G = W @ W^T  (64x64). One block.
// ---------------------------------------------------------------------------
__global__ __launch_bounds__(256) void make_G(const float* __restrict__ W,
                                              float* __restrict__ G) {
    __shared__ float Ws[64 * 64];
    for (int t = threadIdx.x; t < 64 * 64; t += 256) Ws[t] = W[t];
    __syncthreads();
    for (int t = threadIdx.x; t < 64 * 64; t += 256) {
        int i = t >> 6, j = t & 63;
        float acc = 0.f;
#pragma unroll 8
        for (int k = 0; k < 64; ++k) acc += Ws[i * 64 + k] * Ws[j * 64 + k];
        G[t] = acc;
    }
}

// ---------------------------------------------------------------------------
// extractor: xh = x@We^T + be ; h0 = xh@U^T + bU ; xU = h0 / nf
// ---------------------------------------------------------------------------
__global__ __launch_bounds__(256) void extractor(
        const float* __restrict__ x, const float* __restrict__ nf,
        const float* __restrict__ We, const float* __restrict__ be,
        const float* __restrict__ U,  const float* __restrict__ bU,
        float* __restrict__ xh, float* __restrict__ xU, float* __restrict__ h0) {
    __shared__ float WeT[INC * HH];
    __shared__ float UT[HH * HH];
    __shared__ float beS[HH], bUS[HH];
    __shared__ float xs[4][INC];
    __shared__ float xhs[4][HH];

    for (int t = threadIdx.x; t < INC * HH; t += 256) {
        int j = t >> 7, k = t & 127;
        WeT[k * 64 + j] = We[t];
    }
    for (int t = threadIdx.x; t < HH * HH; t += 256) {
        int j = t >> 6, k = t & 63;
        UT[k * 64 + j] = U[t];
    }
    if (threadIdx.x < 64) { beS[threadIdx.x] = be[threadIdx.x]; bUS[threadIdx.x] = bU[threadIdx.x]; }
    __syncthreads();

    int lane = threadIdx.x & 63;
    int wv   = threadIdx.x >> 6;

    for (int n0 = blockIdx.x * 4; n0 < NN; n0 += gridDim.x * 4) {
        int n = n0 + wv;
        bool valid = n < NN;
        if (valid) {
            xs[wv][lane]      = x[(size_t)n * INC + lane];
            xs[wv][lane + 64] = x[(size_t)n * INC + lane + 64];
        }
        __syncthreads();
        float acc = beS[lane];
        if (valid) {
#pragma unroll 8
            for (int k = 0; k < INC; ++k) acc += xs[wv][k] * WeT[k * 64 + lane];
            xh[n * 64 + lane] = acc;
            xhs[wv][lane] = acc;
        }
        __syncthreads();
        if (valid) {
            float acc2 = bUS[lane];
#pragma unroll 8
            for (int k = 0; k < HH; ++k) acc2 += xhs[wv][k] * UT[k * 64 + lane];
            h0[n * 64 + lane] = acc2;
            xU[n * 64 + lane] = acc2 / nf[n];
        }
        __syncthreads();
    }
}

// ---------------------------------------------------------------------------
// fused step v6 (R11 + slim tanh + eps-fold + first-flag zero init).
// base/deg SGPR-uniform via readfirstlane; full 64-edge chunks fully
// unrolled with literal readlane indices; guarded remainder. No atomics.
// ---------------------------------------------------------------------------
__global__ __launch_bounds__(256) void fused_step(
        const int* __restrict__ adj, const int* __restrict__ offs,
        const int* __restrict__ cnt,
        const float* __restrict__ hcur, float* __restrict__ hnxt,
        const float* __restrict__ nf, const float* __restrict__ gamma,
        const float* __restrict__ beta, const float* __restrict__ Gm,
        const float* __restrict__ xU,
        float* __restrict__ y, float* __restrict__ s, int first, int last) {
    __shared__ float Gs[64 * 64];
    for (int t = threadIdx.x; t < 64 * 64; t += 256) Gs[t] = Gm[t];
    __syncthreads();

    const int lane = threadIdx.x & 63, wv = threadIdx.x >> 6;
    const float g = gamma[lane], b = beta[lane];

    for (int n = blockIdx.x * 4 + wv; n < NN; n += gridDim.x * 4) {
        const int base = __builtin_amdgcn_readfirstlane(offs[n]);
        const int deg  = __builtin_amdgcn_readfirstlane(cnt[n]);
        const float hn = hcur[(size_t)n * 64 + lane];
        float accM = 0.f;
        int sigma = 0;

        // ---- full 64-edge chunks: clamp-free, literal lane indices
        const int nfull = deg >> 6;
        for (int c = 0; c < nfull; ++c) {
            const int ev = adj[base + (c << 6) + lane];
            sigma += 64 - 2 * (int)__builtin_popcountll(__ballot(ev < 0));

            float hv0, hv1, hv2, hv3;
            {
                int e0 = __builtin_amdgcn_readlane(ev, 0);
                int e1 = __builtin_amdgcn_readlane(ev, 1);
                int e2 = __builtin_amdgcn_readlane(ev, 2);
                int e3 = __builtin_amdgcn_readlane(ev, 3);
                hv0 = hcur[(size_t)((unsigned)e0 & 0x7fffffffu) * 64u + lane];
                hv1 = hcur[(size_t)((unsigned)e1 & 0x7fffffffu) * 64u + lane];
                hv2 = hcur[(size_t)((unsigned)e2 & 0x7fffffffu) * 64u + lane];
                hv3 = hcur[(size_t)((unsigned)e3 & 0x7fffffffu) * 64u + lane];
            }
#pragma unroll
            for (int q = 0; q < 16; ++q) {
                const int j0 = q << 2;
                // wraparound prefetch: at q=15 re-loads edges 0..3 (discarded)
                int e0 = __builtin_amdgcn_readlane(ev, (j0 + 4) & 63);
                int e1 = __builtin_amdgcn_readlane(ev, (j0 + 5) & 63);
                int e2 = __builtin_amdgcn_readlane(ev, (j0 + 6) & 63);
                int e3 = __builtin_amdgcn_readlane(ev, (j0 + 7) & 63);
                float n0 = hcur[(size_t)((unsigned)e0 & 0x7fffffffu) * 64u + lane];
                float n1 = hcur[(size_t)((unsigned)e1 & 0x7fffffffu) * 64u + lane];
                float n2 = hcur[(size_t)((unsigned)e2 & 0x7fffffffu) * 64u + lane];
                float n3 = hcur[(size_t)((unsigned)e3 & 0x7fffffffu) * 64u + lane];

                accM += quad_contrib<false>(hn, hv0, hv1, hv2, hv3, 0, 64);

                hv0 = n0; hv1 = n1; hv2 = n2; hv3 = n3;
            }
        }

        // ---- remainder chunk (deg & 63 edges), guarded
        const int rem = deg & 63;
        if (rem) {
            const int rbase = base + (nfull << 6);
            int li = lane < rem ? lane : rem - 1;
            int ev = adj[rbase + li];
            unsigned long long bal = __ballot(ev < 0);
            unsigned long long msk = (1ull << rem) - 1ull;
            sigma += rem - 2 * (int)__builtin_popcountll(bal & msk);

            float hv0, hv1, hv2, hv3;
            {
                int j1 = 1 < rem ? 1 : rem - 1;
                int j2 = 2 < rem ? 2 : rem - 1;
                int j3 = 3 < rem ? 3 : rem - 1;
                int e0 = __builtin_amdgcn_readlane(ev, 0);
                int e1 = __builtin_amdgcn_readlane(ev, j1);
                int e2 = __builtin_amdgcn_readlane(ev, j2);
                int e3 = __builtin_amdgcn_readlane(ev, j3);
                hv0 = hcur[(size_t)((unsigned)e0 & 0x7fffffffu) * 64u + lane];
                hv1 = hcur[(size_t)((unsigned)e1 & 0x7fffffffu) * 64u + lane];
                hv2 = hcur[(size_t)((unsigned)e2 & 0x7fffffffu) * 64u + lane];
                hv3 = hcur[(size_t)((unsigned)e3 & 0x7fffffffu) * 64u + lane];
            }
            const int quads = (rem + 3) >> 2;
            for (int q = 0; q < quads; ++q) {
                const int j0 = q << 2;
                int ja = j0 + 4; ja = ja < rem ? ja : rem - 1;
                int jb = j0 + 5; jb = jb < rem ? jb : rem - 1;
                int jc = j0 + 6; jc = jc < rem ? jc : rem - 1;
                int jd = j0 + 7; jd = jd < rem ? jd : rem - 1;
                int e0 = __builtin_amdgcn_readlane(ev, ja);
                int e1 = __builtin_amdgcn_readlane(ev, jb);
                int e2 = __builtin_amdgcn_readlane(ev, jc);
                int e3 = __builtin_amdgcn_readlane(ev, jd);
                float n0 = hcur[(size_t)((unsigned)e0 & 0x7fffffffu) * 64u + lane];
                float n1 = hcur[(size_t)((unsigned)e1 & 0x7fffffffu) * 64u + lane];
                float n2 = hcur[(size_t)((unsigned)e2 & 0x7fffffffu) * 64u + lane];
                float n3 = hcur[(size_t)((unsigned)e3 & 0x7fffffffu) * 64u + lane];

                accM += quad_contrib<true>(hn, hv0, hv1, hv2, hv3, j0, rem);

                hv0 = n0; hv1 = n1; hv2 = n2; hv3 = n3;
            }
        }

        const float nfn = nf[n];
        const float av  = nfn * __builtin_fmaf(g, accM, b * (float)sigma);

        // p[lane] = sum_k av(lane k) * G[k][lane] via readlane broadcast
        float p = 0.f;
        const int avi = __float_as_int(av);
#pragma unroll
        for (int k = 0; k < 64; ++k) {
            float ak = __int_as_float(__builtin_amdgcn_readlane(avi, k));
            p = __builtin_fmaf(ak, Gs[k * 64 + lane], p);
        }

        float yprev = 0.f, sprev = 0.f;
        if (!first) {
            yprev = y[n * 64 + lane];
            sprev = s[n * 64 + lane];
        }
        const float yv = -ALPHA * p + (1.0f - ALPHA) * yprev;
        y[n * 64 + lane] = yv;
        s[n * 64 + lane] = (1.0f - ALPHA) * sprev + av;
        if (!last) hnxt[n * 64 + lane] = nfn * (yv + xU[n * 64 + lane]);
    }
}

// ---------------------------------------------------------------------------
// final: z = -alpha*(s@W) ; zf = nf*z + xh ; out = zf@Wlast^T + blast
// ---------------------------------------------------------------------------
__global__ __launch_bounds__(256) void final_out(
        const float* __restrict__ s, const float* __restrict__ xh,
        const float* __restrict__ nf, const float* __restrict__ W,
        const float* __restrict__ Wlast, const float* __restrict__ blast,
        float* __restrict__ out) {
    __shared__ float Ws[64 * 64];
    __shared__ float WlT[64 * OUTC];
    __shared__ float blS[OUTC];
    __shared__ float ss[4][64];
    __shared__ float zfs[4][64];
    for (int t = threadIdx.x; t < 64 * 64; t += 256) Ws[t] = W[t];
    for (int t = threadIdx.x; t < OUTC * 64; t += 256) {
        int o = t >> 6, j = t & 63;
        WlT[j * OUTC + o] = Wlast[t];
    }
    if (threadIdx.x < OUTC) blS[threadIdx.x] = blast[threadIdx.x];
    __syncthreads();
    int lane = threadIdx.x & 63, wv = threadIdx.x >> 6;
    for (int n0 = blockIdx.x * 4; n0 < NN; n0 += gridDim.x * 4) {
        int n = n0 + wv;
        if (n < NN) ss[wv][lane] = s[n * 64 + lane];
        __syncthreads();
        if (n < NN) {
            float z = 0.f;
#pragma unroll 8
            for (int k = 0; k < 64; ++k) z += ss[wv][k] * Ws[k * 64 + lane];
            z *= -ALPHA;
            zfs[wv][lane] = nf[n] * z + xh[n * 64 + lane];
        }
        __syncthreads();
        if (n < NN && lane < OUTC) {
            float acc = blS[lane];
#pragma unroll 8
            for (int j = 0; j < 64; ++j) acc += zfs[wv][j] * WlT[j * OUTC + lane];
            out[n * OUTC + lane] = acc;
        }
        __syncthreads();
    }
}

// ---------------------------------------------------------------------------
extern "C" void kernel_launch(void* const* d_in, const int* in_sizes, int n_in,
                              void* d_out, int out_size, void* d_ws, size_t ws_size,
                              hipStream_t stream) {
    const float* x     = (const float*)d_in[0];
    const int*   ei    = (const int*)  d_in[1];
    const float* nf    = (const float*)d_in[2];
    const float* We    = (const float*)d_in[3];
    const float* be    = (const float*)d_in[4];
    const float* W     = (const float*)d_in[5];
    const float* U     = (const float*)d_in[6];
    const float* bU    = (const float*)d_in[7];
    const float* gamma = (const float*)d_in[8];
    const float* beta  = (const float*)d_in[9];
    const float* Wlast = (const float*)d_in[10];
    const float* blast = (const float*)d_in[11];
    float* out = (float*)d_out;

    char* ws = (char*)d_ws;
    size_t off = 0;
    const size_t NH = (size_t)NN * HH * sizeof(float);
    int*   adj    = (int*)(ws + off);            off += (size_t)2 * EE * sizeof(int);
    unsigned short* rank16 = (unsigned short*)(ws + off);
                                                 off += (size_t)2 * EE * sizeof(unsigned short);
    int*   offs   = (int*)(ws + off);            off += (size_t)NN * sizeof(int);
    int*   cnt    = (int*)(ws + off);            off += (size_t)NN * sizeof(int);
    int*   bsum   = (int*)(ws + off);            off += 256 * sizeof(int);
    float* xh     = (float*)(ws + off);          off += NH;
    float* xU     = (float*)(ws + off);          off += NH;
    float* h0     = (float*)(ws + off);          off += NH;
    float* h1     = (float*)(ws + off);          off += NH;
    float* y      = (float*)(ws + off);          off += NH;
    float* s      = (float*)(ws + off);          off += NH;
    float* G      = (float*)(ws + off);          off += (size_t)HH * HH * sizeof(float);

    hipMemsetAsync(cnt, 0, (size_t)NN * sizeof(int), stream);
    // y/s zero-init folded into fused_step (first=1)

    // CSR build (once per launch): atomic count (+rank capture), scan,
    // atomic-free fill.
    csr_count<<<(2 * EE + 255) / 256, 256, 0, stream>>>(ei, cnt, rank16);
    scanA<<<NB_SCAN, 256, 0, stream>>>(cnt, offs, bsum);
    scanB<<<1, 256, 0, stream>>>(bsum);
    scanC<<<NB_SCAN, 256, 0, stream>>>(offs, bsum);
    csr_fill<<<(2 * EE + 255) / 256, 256, 0, stream>>>(ei, offs, rank16, adj);

    make_G<<<1, 256, 0, stream>>>(W, G);
    extractor<<<2048, 256, 0, stream>>>(x, nf, We, be, U, bU, xh, xU, h0);

    float* hc = h0;
    float* hn = h1;
    for (int t = 0; t < 4; ++t) {
        fused_step<<<2048, 256, 0, stream>>>(adj, offs, cnt, hc, hn, nf,
                                             gamma, beta, G, xU, y, s,
                                             t == 0, t == 3);
        float* tmp = hc; hc = hn; hn = tmp;
    }
    final_out<<<2048, 256, 0, stream>>>(s, xh, nf, W, Wlast, blast, out);
}